// Round 2
// baseline (2044.886 us; speedup 1.0000x reference)
//
#include <hip/hip_runtime.h>

#define DI __device__ __forceinline__

// ---------------------------------------------------------------------------
// Kernel 1: inverse channel norms for fq_feats / fs_feats (fp32).
// rq[lb*1024+pos] = 1/max(||fq_feats[l,b,:,pos]||, eps). 2 positions/thread.
// ---------------------------------------------------------------------------
__global__ __launch_bounds__(256) void k_norms(const float* __restrict__ fqf,
                                               const float* __restrict__ fsf,
                                               float* __restrict__ rq,
                                               float* __restrict__ rs) {
    int id = blockIdx.x * 256 + threadIdx.x;  // 0..36863
    int tensor = id / 18432;                  // block-uniform
    int r = id % 18432;
    int lb = r >> 9;
    int pp = (r & 511) * 2;
    const float* src = tensor ? fsf : fqf;
    float* dst = tensor ? rs : rq;
    const float* p = src + (size_t)lb * 524288 + pp;
    float s0 = 0.f, s1 = 0.f;
    for (int c = 0; c < 512; ++c) {
        float2 v = *(const float2*)(p + (size_t)c * 1024);
        s0 += v.x * v.x;
        s1 += v.y * v.y;
    }
    float* d = dst + lb * 1024 + pp;
    d[0] = 1.f / fmaxf(sqrtf(s0), 1e-12f);
    d[1] = 1.f / fmaxf(sqrtf(s1), 1e-12f);
}

// ---------------------------------------------------------------------------
// Kernel 2: corr_sum[b,q,s] = sum_l relu( dot_c(fq,fs) * rq * rs )
// 64x64 tile / block, 4x4 register tile, fp32. Grid (16,16,4).
// Stores the SUM over levels (mean /9 folded into softmax temperature).
// ---------------------------------------------------------------------------
__global__ __launch_bounds__(256) void k_corr(const float* __restrict__ fqf,
                                              const float* __restrict__ fsf,
                                              const float* __restrict__ rq,
                                              const float* __restrict__ rs,
                                              float* __restrict__ corr) {
    __shared__ float As[32 * 68];  // [k][q] rows padded to 68 for bank spread
    __shared__ float Bs[32 * 68];  // [k][s]
    const int b = blockIdx.z;
    const int q0 = blockIdx.y * 64;
    const int s0 = blockIdx.x * 64;
    const int t = threadIdx.x;
    const int ty = t >> 4, tx = t & 15;
    const int sk = t >> 3, sq = (t & 7) * 8;

    float accM[4][4] = {};
    for (int l = 0; l < 9; ++l) {
        const int lb = l * 4 + b;
        const float* Ag = fqf + (size_t)lb * 524288 + q0 + sq;
        const float* Bg = fsf + (size_t)lb * 524288 + s0 + sq;
        float accL[4][4] = {};
        for (int k0 = 0; k0 < 512; k0 += 32) {
            float4 a0 = *(const float4*)(Ag + (size_t)(k0 + sk) * 1024);
            float4 a1 = *(const float4*)(Ag + (size_t)(k0 + sk) * 1024 + 4);
            float4 b0 = *(const float4*)(Bg + (size_t)(k0 + sk) * 1024);
            float4 b1 = *(const float4*)(Bg + (size_t)(k0 + sk) * 1024 + 4);
            __syncthreads();  // previous compute done before overwrite
            float* ap = &As[sk * 68 + sq];
            *(float4*)ap = a0;
            *(float4*)(ap + 4) = a1;
            float* bp = &Bs[sk * 68 + sq];
            *(float4*)bp = b0;
            *(float4*)(bp + 4) = b1;
            __syncthreads();
#pragma unroll
            for (int k = 0; k < 32; ++k) {
                float4 a4 = *(const float4*)&As[k * 68 + ty * 4];
                float4 b4 = *(const float4*)&Bs[k * 68 + tx * 4];
                float ar[4] = {a4.x, a4.y, a4.z, a4.w};
                float br[4] = {b4.x, b4.y, b4.z, b4.w};
#pragma unroll
                for (int i = 0; i < 4; ++i)
#pragma unroll
                    for (int j = 0; j < 4; ++j)
                        accL[i][j] = fmaf(ar[i], br[j], accL[i][j]);
            }
        }
        const float* rqp = rq + lb * 1024 + q0 + ty * 4;
        const float* rsp = rs + lb * 1024 + s0 + tx * 4;
        float rqr[4], rsr[4];
#pragma unroll
        for (int i = 0; i < 4; ++i) { rqr[i] = rqp[i]; rsr[i] = rsp[i]; }
#pragma unroll
        for (int i = 0; i < 4; ++i)
#pragma unroll
            for (int j = 0; j < 4; ++j)
                accM[i][j] += fmaxf(accL[i][j] * rqr[i] * rsr[j], 0.f);
    }
#pragma unroll
    for (int i = 0; i < 4; ++i) {
        float* cp = corr + ((size_t)(b * 1024 + q0 + ty * 4 + i)) * 1024 + s0 + tx * 4;
        *(float4*)cp = make_float4(accM[i][0], accM[i][1], accM[i][2], accM[i][3]);
    }
}

// ---------------------------------------------------------------------------
// Kernel 3: in-place row softmax over s, scale = TEMP/9 (mean fold). 1 row/block.
// ---------------------------------------------------------------------------
__global__ __launch_bounds__(256) void k_softmax(float* __restrict__ corr) {
    __shared__ float red[8];
    const size_t row = blockIdx.x;
    float4* p = (float4*)(corr + (row << 10));
    const int t = threadIdx.x;
    float4 v = p[t];
    const float SC = 20.f / 9.f;
    v.x *= SC; v.y *= SC; v.z *= SC; v.w *= SC;
    float m = fmaxf(fmaxf(v.x, v.y), fmaxf(v.z, v.w));
#pragma unroll
    for (int off = 32; off >= 1; off >>= 1) m = fmaxf(m, __shfl_down(m, off));
    const int wid = t >> 6, lane = t & 63;
    if (lane == 0) red[wid] = m;
    __syncthreads();
    m = fmaxf(fmaxf(red[0], red[1]), fmaxf(red[2], red[3]));
    float e0 = __expf(v.x - m), e1 = __expf(v.y - m);
    float e2 = __expf(v.z - m), e3 = __expf(v.w - m);
    float s = e0 + e1 + e2 + e3;
#pragma unroll
    for (int off = 32; off >= 1; off >>= 1) s += __shfl_down(s, off);
    if (lane == 0) red[4 + wid] = s;
    __syncthreads();
    s = red[4] + red[5] + red[6] + red[7];
    float inv = 1.f / s;
    p[t] = make_float4(e0 * inv, e1 * inv, e2 * inv, e3 * inv);
}

// ---------------------------------------------------------------------------
// Kernel 4: att_fq[b,c,q] = sum_s attn[b,q,s] * f_s[b,c,s]  (fp32 out to ws)
// 64c x 64q tile, both operands K-contiguous -> [row][k] LDS, pad 33.
// ---------------------------------------------------------------------------
__global__ __launch_bounds__(256) void k_attfq(const float* __restrict__ fsi,
                                               const float* __restrict__ attn,
                                               float* __restrict__ attfq) {
    __shared__ float As[64 * 33];  // f_s tile [c][k]
    __shared__ float Bs[64 * 33];  // attn tile [q][k]
    const int b = blockIdx.z;
    const int c0 = blockIdx.y * 64;
    const int q0 = blockIdx.x * 64;
    const int t = threadIdx.x;
    const int ty = t >> 4, tx = t & 15;
    const int srow = t >> 2, sk = (t & 3) * 8;
    const float* Ag = fsi + (((size_t)(b * 512 + c0 + srow)) << 10) + sk;
    const float* Bg = attn + (((size_t)(b * 1024 + q0 + srow)) << 10) + sk;
    float acc[4][4] = {};
    for (int s0 = 0; s0 < 1024; s0 += 32) {
        float4 a0 = *(const float4*)(Ag + s0);
        float4 a1 = *(const float4*)(Ag + s0 + 4);
        float4 b0 = *(const float4*)(Bg + s0);
        float4 b1 = *(const float4*)(Bg + s0 + 4);
        __syncthreads();
        float* ap = &As[srow * 33 + sk];
        ap[0] = a0.x; ap[1] = a0.y; ap[2] = a0.z; ap[3] = a0.w;
        ap[4] = a1.x; ap[5] = a1.y; ap[6] = a1.z; ap[7] = a1.w;
        float* bp = &Bs[srow * 33 + sk];
        bp[0] = b0.x; bp[1] = b0.y; bp[2] = b0.z; bp[3] = b0.w;
        bp[4] = b1.x; bp[5] = b1.y; bp[6] = b1.z; bp[7] = b1.w;
        __syncthreads();
#pragma unroll
        for (int k = 0; k < 32; ++k) {
            float ar[4], br[4];
#pragma unroll
            for (int i = 0; i < 4; ++i) ar[i] = As[(ty * 4 + i) * 33 + k];
#pragma unroll
            for (int j = 0; j < 4; ++j) br[j] = Bs[(tx * 4 + j) * 33 + k];
#pragma unroll
            for (int i = 0; i < 4; ++i)
#pragma unroll
                for (int j = 0; j < 4; ++j)
                    acc[i][j] = fmaf(ar[i], br[j], acc[i][j]);
        }
    }
#pragma unroll
    for (int i = 0; i < 4; ++i) {
        float* op = attfq + (((size_t)(b * 512 + c0 + ty * 4 + i)) << 10) + q0 + tx * 4;
        *(float4*)op = make_float4(acc[i][0], acc[i][1], acc[i][2], acc[i][3]);
    }
}

// ---------------------------------------------------------------------------
// Kernel 5: fq = l2n(f_q,C) + 0.5*l2n(att_fq,C); write fq & att_fq (fp32).
// ---------------------------------------------------------------------------
__global__ __launch_bounds__(256) void k_out(const float* __restrict__ fqi,
                                             const float* __restrict__ attfq,
                                             float* __restrict__ out) {
    int id = blockIdx.x * 256 + threadIdx.x;  // 0..2047
    int b = id >> 9;
    int pp = (id & 511) * 2;
    const float* qp = fqi + (((size_t)b) << 19) + pp;
    const float* ap = attfq + (((size_t)b) << 19) + pp;
    float sq0 = 0.f, sq1 = 0.f, sa0 = 0.f, sa1 = 0.f;
    for (int c = 0; c < 512; ++c) {
        float2 q = *(const float2*)(qp + (size_t)c * 1024);
        float2 a = *(const float2*)(ap + (size_t)c * 1024);
        sq0 += q.x * q.x; sq1 += q.y * q.y;
        sa0 += a.x * a.x; sa1 += a.y * a.y;
    }
    float rnq0 = 1.f / fmaxf(sqrtf(sq0), 1e-12f), rnq1 = 1.f / fmaxf(sqrtf(sq1), 1e-12f);
    float rna0 = 1.f / fmaxf(sqrtf(sa0), 1e-12f), rna1 = 1.f / fmaxf(sqrtf(sa1), 1e-12f);
    float* o1 = out + (((size_t)b) << 19) + pp;
    float* o2 = o1 + 2097152;
    for (int c = 0; c < 512; ++c) {
        float2 q = *(const float2*)(qp + (size_t)c * 1024);
        float2 a = *(const float2*)(ap + (size_t)c * 1024);
        float f0 = q.x * rnq0 + 0.5f * a.x * rna0;
        float f1 = q.y * rnq1 + 0.5f * a.y * rna1;
        *(float2*)(o1 + (size_t)c * 1024) = make_float2(f0, f1);
        *(float2*)(o2 + (size_t)c * 1024) = a;
    }
}

// ---------------------------------------------------------------------------
// Kernel 6: conv1 3x3 dil=2 pad=2 over comp=concat(f_q,f_s) [1024ch] -> relu
// 4 oc/block, 4 pos/thread, zero-halo LDS (rows padded to 40).
// ---------------------------------------------------------------------------
__global__ __launch_bounds__(256) void k_conv1(const float* __restrict__ fqi,
                                               const float* __restrict__ fsi,
                                               const float* __restrict__ w1,
                                               const float* __restrict__ b1,
                                               float* __restrict__ x1) {
    __shared__ float in_lds[4 * 36 * 40];
    __shared__ float w_lds[144];
    const int b = blockIdx.y;
    const int oc0 = blockIdx.x * 4;
    const int t = threadIdx.x;
    const int y = t >> 3, x0 = (t & 7) * 4;
    for (int i = t; i < 4 * 36 * 40; i += 256) in_lds[i] = 0.f;
    float acc[4][4];
#pragma unroll
    for (int oi = 0; oi < 4; ++oi) {
        float bb = b1[oc0 + oi];
#pragma unroll
        for (int j = 0; j < 4; ++j) acc[oi][j] = bb;
    }
    for (int ic0 = 0; ic0 < 1024; ic0 += 4) {
        float4 gv[4];
#pragma unroll
        for (int i = 0; i < 4; ++i) {
            int idx4 = i * 256 + t;           // 0..1023
            int icc = idx4 >> 8;              // 0..3
            int pos4 = (idx4 & 255) * 4;      // 0..1020
            int ch = ic0 + icc;
            const float* src = (ch < 512)
                ? (fqi + (((size_t)(b * 512 + ch)) << 10))
                : (fsi + (((size_t)(b * 512 + ch - 512)) << 10));
            gv[i] = *(const float4*)(src + pos4);
        }
        float wreg = 0.f;
        if (t < 144) {
            int oi = t / 36, rem = t % 36;
            wreg = w1[((size_t)(oc0 + oi) * 1024 + ic0 + rem / 9) * 9 + rem % 9];
        }
        __syncthreads();
#pragma unroll
        for (int i = 0; i < 4; ++i) {
            int idx4 = i * 256 + t;
            int icc = idx4 >> 8;
            int pos4 = (idx4 & 255) * 4;
            int py = pos4 >> 5, px = pos4 & 31;
            float* dp = &in_lds[icc * 1440 + (py + 2) * 40 + px + 2];
            dp[0] = gv[i].x; dp[1] = gv[i].y; dp[2] = gv[i].z; dp[3] = gv[i].w;
        }
        if (t < 144) w_lds[t] = wreg;
        __syncthreads();
#pragma unroll
        for (int icc = 0; icc < 4; ++icc) {
            float wv[9][4];
#pragma unroll
            for (int oi = 0; oi < 4; ++oi)
#pragma unroll
                for (int tp = 0; tp < 9; ++tp)
                    wv[tp][oi] = w_lds[oi * 36 + icc * 9 + tp];
#pragma unroll
            for (int kh = 0; kh < 3; ++kh) {
                const float* rp = &in_lds[icc * 1440 + (y + 2 * kh) * 40 + x0];
                float4 ra = *(const float4*)rp;
                float4 rb = *(const float4*)(rp + 4);
                float r[8] = {ra.x, ra.y, ra.z, ra.w, rb.x, rb.y, rb.z, rb.w};
#pragma unroll
                for (int kw = 0; kw < 3; ++kw)
#pragma unroll
                    for (int oi = 0; oi < 4; ++oi)
#pragma unroll
                        for (int j = 0; j < 4; ++j)
                            acc[oi][j] = fmaf(wv[kh * 3 + kw][oi], r[j + 2 * kw], acc[oi][j]);
            }
        }
        __syncthreads();
    }
#pragma unroll
    for (int oi = 0; oi < 4; ++oi) {
        float* xp = x1 + (((size_t)(b * 256 + oc0 + oi)) << 10) + y * 32 + x0;
        *(float4*)xp = make_float4(fmaxf(acc[oi][0], 0.f), fmaxf(acc[oi][1], 0.f),
                                   fmaxf(acc[oi][2], 0.f), fmaxf(acc[oi][3], 0.f));
    }
}

// ---------------------------------------------------------------------------
// Kernel 7: conv2 3x3 valid on x1 [256ch,32,32] -> x2 [256,30,30] (no relu)
// ---------------------------------------------------------------------------
__global__ __launch_bounds__(256) void k_conv2(const float* __restrict__ x1,
                                               const float* __restrict__ w2,
                                               const float* __restrict__ b2,
                                               float* __restrict__ x2) {
    __shared__ float in_lds[4 * 1024];
    __shared__ float w_lds[144];
    const int b = blockIdx.y;
    const int oc0 = blockIdx.x * 4;
    const int t = threadIdx.x;
    int py[4], px[4];
    bool valid[4];
#pragma unroll
    for (int j = 0; j < 4; ++j) {
        int p = t + j * 256;
        valid[j] = p < 900;
        if (valid[j]) { py[j] = p / 30; px[j] = p % 30; }
        else { py[j] = 0; px[j] = 0; }
    }
    float acc[4][4];
#pragma unroll
    for (int oi = 0; oi < 4; ++oi) {
        float bb = b2[oc0 + oi];
#pragma unroll
        for (int j = 0; j < 4; ++j) acc[oi][j] = bb;
    }
    for (int ic0 = 0; ic0 < 256; ic0 += 4) {
        float4 gv[4];
#pragma unroll
        for (int i = 0; i < 4; ++i) {
            int idx4 = i * 256 + t;
            int icc = idx4 >> 8;
            int pos4 = (idx4 & 255) * 4;
            gv[i] = *(const float4*)(x1 + (((size_t)(b * 256 + ic0 + icc)) << 10) + pos4);
        }
        float wreg = 0.f;
        if (t < 144) {
            int oi = t / 36, rem = t % 36;
            wreg = w2[((size_t)(oc0 + oi) * 256 + ic0 + rem / 9) * 9 + rem % 9];
        }
        __syncthreads();
#pragma unroll
        for (int i = 0; i < 4; ++i) {
            int idx4 = i * 256 + t;
            int icc = idx4 >> 8;
            int pos4 = (idx4 & 255) * 4;
            *(float4*)&in_lds[icc * 1024 + pos4] = gv[i];
        }
        if (t < 144) w_lds[t] = wreg;
        __syncthreads();
#pragma unroll
        for (int icc = 0; icc < 4; ++icc) {
            float wv[9][4];
#pragma unroll
            for (int oi = 0; oi < 4; ++oi)
#pragma unroll
                for (int tp = 0; tp < 9; ++tp)
                    wv[tp][oi] = w_lds[oi * 36 + icc * 9 + tp];
#pragma unroll
            for (int kh = 0; kh < 3; ++kh)
#pragma unroll
                for (int kw = 0; kw < 3; ++kw)
#pragma unroll
                    for (int j = 0; j < 4; ++j) {
                        float iv = in_lds[icc * 1024 + (py[j] + kh) * 32 + px[j] + kw];
#pragma unroll
                        for (int oi = 0; oi < 4; ++oi)
                            acc[oi][j] = fmaf(wv[kh * 3 + kw][oi], iv, acc[oi][j]);
                    }
        }
        __syncthreads();
    }
#pragma unroll
    for (int j = 0; j < 4; ++j)
        if (valid[j])
#pragma unroll
            for (int oi = 0; oi < 4; ++oi)
                x2[((size_t)(b * 256 + oc0 + oi)) * 900 + t + j * 256] = acc[oi][j];
}

// ---------------------------------------------------------------------------
// Kernel 8: 3x3/3 maxpool (30x30 -> 10x10)
// ---------------------------------------------------------------------------
__global__ __launch_bounds__(256) void k_pool(const float* __restrict__ x2,
                                              float* __restrict__ xp) {
    int id = blockIdx.x * 256 + threadIdx.x;
    if (id >= 102400) return;
    int px = id % 10;
    int tmp = id / 10;
    int py = tmp % 10;
    int ch = tmp / 10;
    const float* ip = x2 + (size_t)ch * 900 + (3 * py) * 30 + 3 * px;
    float m = ip[0];
#pragma unroll
    for (int dy = 0; dy < 3; ++dy)
#pragma unroll
        for (int dx = 0; dx < 3; ++dx) m = fmaxf(m, ip[dy * 30 + dx]);
    xp[id] = m;
}

// ---------------------------------------------------------------------------
// Kernel 9: conv3 (256ch, 10x10 -> 8x8) + spatial mean + b3 -> weight[1,B]
// ---------------------------------------------------------------------------
__global__ __launch_bounds__(256) void k_conv3(const float* __restrict__ xp,
                                               const float* __restrict__ w3,
                                               const float* __restrict__ b3,
                                               float* __restrict__ out) {
    __shared__ float s[256];
    int b = blockIdx.x, t = threadIdx.x;
    int pos = t & 63, qi = t >> 6;
    int y = pos >> 3, x = pos & 7;
    float acc = 0.f;
    for (int ic = qi * 64; ic < qi * 64 + 64; ++ic) {
        const float* ip = xp + ((size_t)(b * 256 + ic)) * 100 + y * 10 + x;
#pragma unroll
        for (int kh = 0; kh < 3; ++kh)
#pragma unroll
            for (int kw = 0; kw < 3; ++kw)
                acc = fmaf(w3[ic * 9 + kh * 3 + kw], ip[kh * 10 + kw], acc);
    }
    s[t] = acc;
    __syncthreads();
    if (t < 64) {
        float v = s[t] + s[t + 64] + s[t + 128] + s[t + 192];
#pragma unroll
        for (int off = 32; off >= 1; off >>= 1) v += __shfl_down(v, off);
        if (t == 0) out[4194304 + b] = v * (1.f / 64.f) + b3[0];
    }
}

// ---------------------------------------------------------------------------
extern "C" void kernel_launch(void* const* d_in, const int* in_sizes, int n_in,
                              void* d_out, int out_size, void* d_ws, size_t ws_size,
                              hipStream_t stream) {
    (void)in_sizes; (void)n_in; (void)out_size; (void)ws_size;
    const float* fqf = (const float*)d_in[0];  // fq_feats [9,4,512,32,32]
    const float* fsf = (const float*)d_in[1];  // fs_feats
    const float* fqi = (const float*)d_in[2];  // f_q [4,512,32,32]
    const float* fsi = (const float*)d_in[3];  // f_s
    const float* w1  = (const float*)d_in[4];
    const float* b1  = (const float*)d_in[5];
    const float* w2  = (const float*)d_in[6];
    const float* b2  = (const float*)d_in[7];
    const float* w3  = (const float*)d_in[8];
    const float* b3  = (const float*)d_in[9];
    float* out = (float*)d_out;

    float* W = (float*)d_ws;
    float* corr  = W;              // 4,194,304 f32 (16 MB), reused as attn
    float* rq    = W + 4194304;    //    36,864
    float* rs    = W + 4231168;    //    36,864
    float* attfq = W + 4268032;    // 2,097,152
    float* x1    = W + 6365184;    // 1,048,576
    float* x2    = W + 7413760;    //   921,600
    float* xp    = W + 8335360;    //   102,400   (end: 8,437,760 f32 = 33.8 MB)

    hipLaunchKernelGGL(k_norms,   dim3(144),       dim3(256), 0, stream, fqf, fsf, rq, rs);
    hipLaunchKernelGGL(k_corr,    dim3(16, 16, 4), dim3(256), 0, stream, fqf, fsf, rq, rs, corr);
    hipLaunchKernelGGL(k_softmax, dim3(4096),      dim3(256), 0, stream, corr);
    hipLaunchKernelGGL(k_attfq,   dim3(16, 8, 4),  dim3(256), 0, stream, fsi, corr, attfq);
    hipLaunchKernelGGL(k_out,     dim3(8),         dim3(256), 0, stream, fqi, attfq, out);
    hipLaunchKernelGGL(k_conv1,   dim3(64, 4),     dim3(256), 0, stream, fqi, fsi, w1, b1, x1);
    hipLaunchKernelGGL(k_conv2,   dim3(64, 4),     dim3(256), 0, stream, x1, w2, b2, x2);
    hipLaunchKernelGGL(k_pool,    dim3(400),       dim3(256), 0, stream, x2, xp);
    hipLaunchKernelGGL(k_conv3,   dim3(4),         dim3(256), 0, stream, xp, w3, b3, out);
}

// Round 3
// 1307.127 us; speedup vs baseline: 1.5644x; 1.5644x over previous
//
#include <hip/hip_runtime.h>
#include <hip/hip_bf16.h>

#define DI __device__ __forceinline__

typedef short bf16x8_t __attribute__((ext_vector_type(8)));
typedef float f32x4_t __attribute__((ext_vector_type(4)));

// ---------------------------------------------------------------------------
// Kernel 1: inverse channel norms for fq_feats / fs_feats (fp32).
// ---------------------------------------------------------------------------
__global__ __launch_bounds__(256) void k_norms(const float* __restrict__ fqf,
                                               const float* __restrict__ fsf,
                                               float* __restrict__ rq,
                                               float* __restrict__ rs) {
    int id = blockIdx.x * 256 + threadIdx.x;  // 0..36863
    int tensor = id / 18432;                  // block-uniform
    int r = id % 18432;
    int lb = r >> 9;
    int pp = (r & 511) * 2;
    const float* src = tensor ? fsf : fqf;
    float* dst = tensor ? rs : rq;
    const float* p = src + (size_t)lb * 524288 + pp;
    float s0 = 0.f, s1 = 0.f;
    for (int c = 0; c < 512; ++c) {
        float2 v = *(const float2*)(p + (size_t)c * 1024);
        s0 += v.x * v.x;
        s1 += v.y * v.y;
    }
    float* d = dst + lb * 1024 + pp;
    d[0] = 1.f / fmaxf(sqrtf(s0), 1e-12f);
    d[1] = 1.f / fmaxf(sqrtf(s1), 1e-12f);
}

// ---------------------------------------------------------------------------
// Kernel 2 (MFMA): corr_sum[b,q,s] = sum_l relu( dot_c(fq,fs) * rq * rs )
// 128x128 block tile, 4 waves x (64x64), BK=32, 9 levels x 16 k-steps.
// fp32 tiles staged via global_load_lds (async, double-buffered); bf16
// conversion at frag build (v_cvt_pk_bf16_f32). Row-rotation swizzle
// (row r rotated by (r>>3)*8 floats) makes the strided frag reads 2-way
// bank-aliased only (free). Per-level ReLU fold in registers.
// ---------------------------------------------------------------------------
DI void stage_tile(const float* gbase, float* lbase, int w, int lane) {
#pragma unroll
    for (int i = 0; i < 4; ++i) {
        int slot = i * 256 + w * 64 + lane;     // 16B slots 0..1023
        int r = slot >> 5;                      // row (k) 0..31
        int chp = slot & 31;                    // physical 16B chunk in row
        int msrc = ((chp * 4) - ((r >> 3) << 3)) & 127;  // un-rotated col
        __builtin_amdgcn_global_load_lds(
            (const __attribute__((address_space(1))) void*)(gbase + (size_t)r * 1024 + msrc),
            (__attribute__((address_space(3))) void*)(lbase + i * 1024 + w * 256),
            16, 0, 0);
    }
}

DI bf16x8_t build_frag(const float* base, int col, int quad) {
    const float* p = base + quad * 1024 + col;  // row quad*8, rotated col
    float f[8];
#pragma unroll
    for (int j = 0; j < 8; ++j) f[j] = p[j * 128];
    union { unsigned u[4]; bf16x8_t v; } r;
#pragma unroll
    for (int j = 0; j < 4; ++j) {
        __hip_bfloat162 h = __float22bfloat162_rn(make_float2(f[2 * j], f[2 * j + 1]));
        unsigned uu;
        __builtin_memcpy(&uu, &h, 4);
        r.u[j] = uu;
    }
    return r.v;
}

__global__ __launch_bounds__(256) void k_corr(const float* __restrict__ fqf,
                                              const float* __restrict__ fsf,
                                              const float* __restrict__ rq,
                                              const float* __restrict__ rs,
                                              float* __restrict__ corr) {
    __shared__ float As[2][4096];  // [buf][32 k x 128 m] fp32, row-rotated
    __shared__ float Bs[2][4096];
    const int b = blockIdx.z;
    const int q0 = blockIdx.y * 128;
    const int s0 = blockIdx.x * 128;
    const int t = threadIdx.x;
    const int w = t >> 6, lane = t & 63;
    const int wrow = w >> 1, wcol = w & 1;   // 2x2 waves of 64x64
    const int quad = lane >> 4, m16 = lane & 15;

    f32x4_t zero4 = {0.f, 0.f, 0.f, 0.f};
    f32x4_t master[4][4], lvl[4][4];
#pragma unroll
    for (int i = 0; i < 4; ++i)
#pragma unroll
        for (int j = 0; j < 4; ++j) { master[i][j] = zero4; lvl[i][j] = zero4; }

    // stage step 0 into buf 0
    {
        const float* Ab = fqf + (size_t)b * 524288 + q0;
        const float* Bb = fsf + (size_t)b * 524288 + s0;
        stage_tile(Ab, &As[0][0], w, lane);
        stage_tile(Bb, &Bs[0][0], w, lane);
    }

    for (int step = 0; step < 144; ++step) {
        const int buf = step & 1;
        __syncthreads();  // waits vmcnt(0): current buf staged; prefetch not yet issued
        if (step < 143) {
            int ns = step + 1;
            int lb = ((ns >> 4) * 4 + b);
            int kk0 = (ns & 15) << 5;
            const float* Ab = fqf + (size_t)lb * 524288 + (size_t)kk0 * 1024 + q0;
            const float* Bb = fsf + (size_t)lb * 524288 + (size_t)kk0 * 1024 + s0;
            stage_tile(Ab, &As[buf ^ 1][0], w, lane);
            stage_tile(Bb, &Bs[buf ^ 1][0], w, lane);
        }
        const float* Ab = &As[buf][0];
        const float* Bb = &Bs[buf][0];
        bf16x8_t af[4], bfr[4];
#pragma unroll
        for (int i = 0; i < 4; ++i) {
            af[i]  = build_frag(Ab, ((wrow * 64 + i * 16 + m16) + quad * 8) & 127, quad);
            bfr[i] = build_frag(Bb, ((wcol * 64 + i * 16 + m16) + quad * 8) & 127, quad);
        }
#pragma unroll
        for (int mi = 0; mi < 4; ++mi)
#pragma unroll
            for (int ni = 0; ni < 4; ++ni)
                lvl[mi][ni] = __builtin_amdgcn_mfma_f32_16x16x32_bf16(
                    af[mi], bfr[ni], lvl[mi][ni], 0, 0, 0);

        if ((step & 15) == 15) {  // per-level epilogue: scale, relu, accumulate
            int lb = (step >> 4) * 4 + b;
            const float* rqb = rq + lb * 1024 + q0 + wrow * 64;
            const float* rsb = rs + lb * 1024 + s0 + wcol * 64;
            float rq4[4][4], rsv[4];
#pragma unroll
            for (int mi = 0; mi < 4; ++mi) {
                float4 v = *(const float4*)(rqb + mi * 16 + quad * 4);
                rq4[mi][0] = v.x; rq4[mi][1] = v.y; rq4[mi][2] = v.z; rq4[mi][3] = v.w;
            }
#pragma unroll
            for (int ni = 0; ni < 4; ++ni) rsv[ni] = rsb[ni * 16 + m16];
#pragma unroll
            for (int mi = 0; mi < 4; ++mi)
#pragma unroll
                for (int ni = 0; ni < 4; ++ni) {
#pragma unroll
                    for (int e = 0; e < 4; ++e)
                        master[mi][ni][e] += fmaxf(lvl[mi][ni][e] * rq4[mi][e] * rsv[ni], 0.f);
                    lvl[mi][ni] = zero4;
                }
        }
    }

#pragma unroll
    for (int mi = 0; mi < 4; ++mi)
#pragma unroll
        for (int e = 0; e < 4; ++e) {
            int q = q0 + wrow * 64 + mi * 16 + quad * 4 + e;
            float* cp = corr + ((size_t)(b * 1024 + q)) * 1024 + s0 + wcol * 64 + m16;
#pragma unroll
            for (int ni = 0; ni < 4; ++ni)
                cp[ni * 16] = master[mi][ni][e];
        }
}

// ---------------------------------------------------------------------------
// Kernel 3: in-place row softmax over s, scale = TEMP/9 (mean fold). 1 row/block.
// ---------------------------------------------------------------------------
__global__ __launch_bounds__(256) void k_softmax(float* __restrict__ corr) {
    __shared__ float red[8];
    const size_t row = blockIdx.x;
    float4* p = (float4*)(corr + (row << 10));
    const int t = threadIdx.x;
    float4 v = p[t];
    const float SC = 20.f / 9.f;
    v.x *= SC; v.y *= SC; v.z *= SC; v.w *= SC;
    float m = fmaxf(fmaxf(v.x, v.y), fmaxf(v.z, v.w));
#pragma unroll
    for (int off = 32; off >= 1; off >>= 1) m = fmaxf(m, __shfl_down(m, off));
    const int wid = t >> 6, lane = t & 63;
    if (lane == 0) red[wid] = m;
    __syncthreads();
    m = fmaxf(fmaxf(red[0], red[1]), fmaxf(red[2], red[3]));
    float e0 = __expf(v.x - m), e1 = __expf(v.y - m);
    float e2 = __expf(v.z - m), e3 = __expf(v.w - m);
    float s = e0 + e1 + e2 + e3;
#pragma unroll
    for (int off = 32; off >= 1; off >>= 1) s += __shfl_down(s, off);
    if (lane == 0) red[4 + wid] = s;
    __syncthreads();
    s = red[4] + red[5] + red[6] + red[7];
    float inv = 1.f / s;
    p[t] = make_float4(e0 * inv, e1 * inv, e2 * inv, e3 * inv);
}

// ---------------------------------------------------------------------------
// Kernel 4: att_fq[b,c,q] = sum_s attn[b,q,s] * f_s[b,c,s]  (fp32 out to ws)
// ---------------------------------------------------------------------------
__global__ __launch_bounds__(256) void k_attfq(const float* __restrict__ fsi,
                                               const float* __restrict__ attn,
                                               float* __restrict__ attfq) {
    __shared__ float As[64 * 33];  // f_s tile [c][k]
    __shared__ float Bs[64 * 33];  // attn tile [q][k]
    const int b = blockIdx.z;
    const int c0 = blockIdx.y * 64;
    const int q0 = blockIdx.x * 64;
    const int t = threadIdx.x;
    const int ty = t >> 4, tx = t & 15;
    const int srow = t >> 2, sk = (t & 3) * 8;
    const float* Ag = fsi + (((size_t)(b * 512 + c0 + srow)) << 10) + sk;
    const float* Bg = attn + (((size_t)(b * 1024 + q0 + srow)) << 10) + sk;
    float acc[4][4] = {};
    for (int s0 = 0; s0 < 1024; s0 += 32) {
        float4 a0 = *(const float4*)(Ag + s0);
        float4 a1 = *(const float4*)(Ag + s0 + 4);
        float4 b0 = *(const float4*)(Bg + s0);
        float4 b1 = *(const float4*)(Bg + s0 + 4);
        __syncthreads();
        float* ap = &As[srow * 33 + sk];
        ap[0] = a0.x; ap[1] = a0.y; ap[2] = a0.z; ap[3] = a0.w;
        ap[4] = a1.x; ap[5] = a1.y; ap[6] = a1.z; ap[7] = a1.w;
        float* bp = &Bs[srow * 33 + sk];
        bp[0] = b0.x; bp[1] = b0.y; bp[2] = b0.z; bp[3] = b0.w;
        bp[4] = b1.x; bp[5] = b1.y; bp[6] = b1.z; bp[7] = b1.w;
        __syncthreads();
#pragma unroll
        for (int k = 0; k < 32; ++k) {
            float ar[4], br[4];
#pragma unroll
            for (int i = 0; i < 4; ++i) ar[i] = As[(ty * 4 + i) * 33 + k];
#pragma unroll
            for (int j = 0; j < 4; ++j) br[j] = Bs[(tx * 4 + j) * 33 + k];
#pragma unroll
            for (int i = 0; i < 4; ++i)
#pragma unroll
                for (int j = 0; j < 4; ++j)
                    acc[i][j] = fmaf(ar[i], br[j], acc[i][j]);
        }
    }
#pragma unroll
    for (int i = 0; i < 4; ++i) {
        float* op = attfq + (((size_t)(b * 512 + c0 + ty * 4 + i)) << 10) + q0 + tx * 4;
        *(float4*)op = make_float4(acc[i][0], acc[i][1], acc[i][2], acc[i][3]);
    }
}

// ---------------------------------------------------------------------------
// Kernel 5: fq = l2n(f_q,C) + 0.5*l2n(att_fq,C); write fq & att_fq (fp32).
// 64 blocks: (b, 64-pos chunk) x 256 thr = 64 pos x 4 c-groups of 128.
// ---------------------------------------------------------------------------
__global__ __launch_bounds__(256) void k_out(const float* __restrict__ fqi,
                                             const float* __restrict__ attfq,
                                             float* __restrict__ out) {
    __shared__ float redq[256], reda[256];
    __shared__ float rnq[64], rna[64];
    const int b = blockIdx.y;
    const int p0 = blockIdx.x * 64;
    const int t = threadIdx.x;
    const int pl = t & 63, cg = t >> 6;
    const int pos = p0 + pl;
    const float* qp = fqi + (((size_t)b) << 19) + pos;
    const float* ap = attfq + (((size_t)b) << 19) + pos;
    float sq = 0.f, sa = 0.f;
    for (int c = cg * 128; c < cg * 128 + 128; ++c) {
        float q = qp[(size_t)c << 10];
        float a = ap[(size_t)c << 10];
        sq += q * q;
        sa += a * a;
    }
    redq[t] = sq; reda[t] = sa;
    __syncthreads();
    if (t < 64) {
        float q = redq[t] + redq[t + 64] + redq[t + 128] + redq[t + 192];
        float a = reda[t] + reda[t + 64] + reda[t + 128] + reda[t + 192];
        rnq[t] = 1.f / fmaxf(sqrtf(q), 1e-12f);
        rna[t] = 1.f / fmaxf(sqrtf(a), 1e-12f);
    }
    __syncthreads();
    const float RQ = rnq[pl], RA = 0.5f * rna[pl];
    float* o1 = out + (((size_t)b) << 19) + pos;
    float* o2 = o1 + 2097152;
    for (int c = cg * 128; c < cg * 128 + 128; ++c) {
        float q = qp[(size_t)c << 10];
        float a = ap[(size_t)c << 10];
        o1[(size_t)c << 10] = q * RQ + a * RA;
        o2[(size_t)c << 10] = a;
    }
}

// ---------------------------------------------------------------------------
// Kernel 6: conv1 3x3 dil=2 pad=2 over comp=concat(f_q,f_s) [1024ch] -> relu
// ---------------------------------------------------------------------------
__global__ __launch_bounds__(256) void k_conv1(const float* __restrict__ fqi,
                                               const float* __restrict__ fsi,
                                               const float* __restrict__ w1,
                                               const float* __restrict__ b1,
                                               float* __restrict__ x1) {
    __shared__ float in_lds[4 * 36 * 40];
    __shared__ float w_lds[144];
    const int b = blockIdx.y;
    const int oc0 = blockIdx.x * 4;
    const int t = threadIdx.x;
    const int y = t >> 3, x0 = (t & 7) * 4;
    for (int i = t; i < 4 * 36 * 40; i += 256) in_lds[i] = 0.f;
    float acc[4][4];
#pragma unroll
    for (int oi = 0; oi < 4; ++oi) {
        float bb = b1[oc0 + oi];
#pragma unroll
        for (int j = 0; j < 4; ++j) acc[oi][j] = bb;
    }
    for (int ic0 = 0; ic0 < 1024; ic0 += 4) {
        float4 gv[4];
#pragma unroll
        for (int i = 0; i < 4; ++i) {
            int idx4 = i * 256 + t;
            int icc = idx4 >> 8;
            int pos4 = (idx4 & 255) * 4;
            int ch = ic0 + icc;
            const float* src = (ch < 512)
                ? (fqi + (((size_t)(b * 512 + ch)) << 10))
                : (fsi + (((size_t)(b * 512 + ch - 512)) << 10));
            gv[i] = *(const float4*)(src + pos4);
        }
        float wreg = 0.f;
        if (t < 144) {
            int oi = t / 36, rem = t % 36;
            wreg = w1[((size_t)(oc0 + oi) * 1024 + ic0 + rem / 9) * 9 + rem % 9];
        }
        __syncthreads();
#pragma unroll
        for (int i = 0; i < 4; ++i) {
            int idx4 = i * 256 + t;
            int icc = idx4 >> 8;
            int pos4 = (idx4 & 255) * 4;
            int py = pos4 >> 5, px = pos4 & 31;
            float* dp = &in_lds[icc * 1440 + (py + 2) * 40 + px + 2];
            dp[0] = gv[i].x; dp[1] = gv[i].y; dp[2] = gv[i].z; dp[3] = gv[i].w;
        }
        if (t < 144) w_lds[t] = wreg;
        __syncthreads();
#pragma unroll
        for (int icc = 0; icc < 4; ++icc) {
            float wv[9][4];
#pragma unroll
            for (int oi = 0; oi < 4; ++oi)
#pragma unroll
                for (int tp = 0; tp < 9; ++tp)
                    wv[tp][oi] = w_lds[oi * 36 + icc * 9 + tp];
#pragma unroll
            for (int kh = 0; kh < 3; ++kh) {
                const float* rp = &in_lds[icc * 1440 + (y + 2 * kh) * 40 + x0];
                float4 ra = *(const float4*)rp;
                float4 rb = *(const float4*)(rp + 4);
                float r[8] = {ra.x, ra.y, ra.z, ra.w, rb.x, rb.y, rb.z, rb.w};
#pragma unroll
                for (int kw = 0; kw < 3; ++kw)
#pragma unroll
                    for (int oi = 0; oi < 4; ++oi)
#pragma unroll
                        for (int j = 0; j < 4; ++j)
                            acc[oi][j] = fmaf(wv[kh * 3 + kw][oi], r[j + 2 * kw], acc[oi][j]);
            }
        }
        __syncthreads();
    }
#pragma unroll
    for (int oi = 0; oi < 4; ++oi) {
        float* xp = x1 + (((size_t)(b * 256 + oc0 + oi)) << 10) + y * 32 + x0;
        *(float4*)xp = make_float4(fmaxf(acc[oi][0], 0.f), fmaxf(acc[oi][1], 0.f),
                                   fmaxf(acc[oi][2], 0.f), fmaxf(acc[oi][3], 0.f));
    }
}

// ---------------------------------------------------------------------------
// Kernel 7: conv2 3x3 valid on x1 [256ch,32,32] -> x2 [256,30,30] (no relu)
// ---------------------------------------------------------------------------
__global__ __launch_bounds__(256) void k_conv2(const float* __restrict__ x1,
                                               const float* __restrict__ w2,
                                               const float* __restrict__ b2,
                                               float* __restrict__ x2) {
    __shared__ float in_lds[4 * 1024];
    __shared__ float w_lds[144];
    const int b = blockIdx.y;
    const int oc0 = blockIdx.x * 4;
    const int t = threadIdx.x;
    int py[4], px[4];
    bool valid[4];
#pragma unroll
    for (int j = 0; j < 4; ++j) {
        int p = t + j * 256;
        valid[j] = p < 900;
        if (valid[j]) { py[j] = p / 30; px[j] = p % 30; }
        else { py[j] = 0; px[j] = 0; }
    }
    float acc[4][4];
#pragma unroll
    for (int oi = 0; oi < 4; ++oi) {
        float bb = b2[oc0 + oi];
#pragma unroll
        for (int j = 0; j < 4; ++j) acc[oi][j] = bb;
    }
    for (int ic0 = 0; ic0 < 256; ic0 += 4) {
        float4 gv[4];
#pragma unroll
        for (int i = 0; i < 4; ++i) {
            int idx4 = i * 256 + t;
            int icc = idx4 >> 8;
            int pos4 = (idx4 & 255) * 4;
            gv[i] = *(const float4*)(x1 + (((size_t)(b * 256 + ic0 + icc)) << 10) + pos4);
        }
        float wreg = 0.f;
        if (t < 144) {
            int oi = t / 36, rem = t % 36;
            wreg = w2[((size_t)(oc0 + oi) * 256 + ic0 + rem / 9) * 9 + rem % 9];
        }
        __syncthreads();
#pragma unroll
        for (int i = 0; i < 4; ++i) {
            int idx4 = i * 256 + t;
            int icc = idx4 >> 8;
            int pos4 = (idx4 & 255) * 4;
            *(float4*)&in_lds[icc * 1024 + pos4] = gv[i];
        }
        if (t < 144) w_lds[t] = wreg;
        __syncthreads();
#pragma unroll
        for (int icc = 0; icc < 4; ++icc) {
            float wv[9][4];
#pragma unroll
            for (int oi = 0; oi < 4; ++oi)
#pragma unroll
                for (int tp = 0; tp < 9; ++tp)
                    wv[tp][oi] = w_lds[oi * 36 + icc * 9 + tp];
#pragma unroll
            for (int kh = 0; kh < 3; ++kh)
#pragma unroll
                for (int kw = 0; kw < 3; ++kw)
#pragma unroll
                    for (int j = 0; j < 4; ++j) {
                        float iv = in_lds[icc * 1024 + (py[j] + kh) * 32 + px[j] + kw];
#pragma unroll
                        for (int oi = 0; oi < 4; ++oi)
                            acc[oi][j] = fmaf(wv[kh * 3 + kw][oi], iv, acc[oi][j]);
                    }
        }
        __syncthreads();
    }
#pragma unroll
    for (int j = 0; j < 4; ++j)
        if (valid[j])
#pragma unroll
            for (int oi = 0; oi < 4; ++oi)
                x2[((size_t)(b * 256 + oc0 + oi)) * 900 + t + j * 256] = acc[oi][j];
}

// ---------------------------------------------------------------------------
// Kernel 8: 3x3/3 maxpool (30x30 -> 10x10)
// ---------------------------------------------------------------------------
__global__ __launch_bounds__(256) void k_pool(const float* __restrict__ x2,
                                              float* __restrict__ xp) {
    int id = blockIdx.x * 256 + threadIdx.x;
    if (id >= 102400) return;
    int px = id % 10;
    int tmp = id / 10;
    int py = tmp % 10;
    int ch = tmp / 10;
    const float* ip = x2 + (size_t)ch * 900 + (3 * py) * 30 + 3 * px;
    float m = ip[0];
#pragma unroll
    for (int dy = 0; dy < 3; ++dy)
#pragma unroll
        for (int dx = 0; dx < 3; ++dx) m = fmaxf(m, ip[dy * 30 + dx]);
    xp[id] = m;
}

// ---------------------------------------------------------------------------
// Kernel 9: conv3 (256ch, 10x10 -> 8x8) + spatial mean + b3 -> weight[1,B]
// ---------------------------------------------------------------------------
__global__ __launch_bounds__(256) void k_conv3(const float* __restrict__ xp,
                                               const float* __restrict__ w3,
                                               const float* __restrict__ b3,
                                               float* __restrict__ out) {
    __shared__ float s[256];
    int b = blockIdx.x, t = threadIdx.x;
    int pos = t & 63, qi = t >> 6;
    int y = pos >> 3, x = pos & 7;
    float acc = 0.f;
    for (int ic = qi * 64; ic < qi * 64 + 64; ++ic) {
        const float* ip = xp + ((size_t)(b * 256 + ic)) * 100 + y * 10 + x;
#pragma unroll
        for (int kh = 0; kh < 3; ++kh)
#pragma unroll
            for (int kw = 0; kw < 3; ++kw)
                acc = fmaf(w3[ic * 9 + kh * 3 + kw], ip[kh * 10 + kw], acc);
    }
    s[t] = acc;
    __syncthreads();
    if (t < 64) {
        float v = s[t] + s[t + 64] + s[t + 128] + s[t + 192];
#pragma unroll
        for (int off = 32; off >= 1; off >>= 1) v += __shfl_down(v, off);
        if (t == 0) out[4194304 + b] = v * (1.f / 64.f) + b3[0];
    }
}

// ---------------------------------------------------------------------------
extern "C" void kernel_launch(void* const* d_in, const int* in_sizes, int n_in,
                              void* d_out, int out_size, void* d_ws, size_t ws_size,
                              hipStream_t stream) {
    (void)in_sizes; (void)n_in; (void)out_size; (void)ws_size;
    const float* fqf = (const float*)d_in[0];  // fq_feats [9,4,512,32,32]
    const float* fsf = (const float*)d_in[1];  // fs_feats
    const float* fqi = (const float*)d_in[2];  // f_q [4,512,32,32]
    const float* fsi = (const float*)d_in[3];  // f_s
    const float* w1  = (const float*)d_in[4];
    const float* b1  = (const float*)d_in[5];
    const float* w2  = (const float*)d_in[6];
    const float* b2  = (const float*)d_in[7];
    const float* w3  = (const float*)d_in[8];
    const float* b3  = (const float*)d_in[9];
    float* out = (float*)d_out;

    float* W = (float*)d_ws;
    float* corr  = W;              // 4,194,304 f32 (16 MB), reused as attn
    float* rq    = W + 4194304;    //    36,864
    float* rs    = W + 4231168;    //    36,864
    float* attfq = W + 4268032;    // 2,097,152
    float* x1    = W + 6365184;    // 1,048,576
    float* x2    = W + 7413760;    //   921,600
    float* xp    = W + 8335360;    //   102,400   (end: 8,437,760 f32 = 33.8 MB)

    hipLaunchKernelGGL(k_norms,   dim3(144),       dim3(256), 0, stream, fqf, fsf, rq, rs);
    hipLaunchKernelGGL(k_corr,    dim3(8, 8, 4),   dim3(256), 0, stream, fqf, fsf, rq, rs, corr);
    hipLaunchKernelGGL(k_softmax, dim3(4096),      dim3(256), 0, stream, corr);
    hipLaunchKernelGGL(k_attfq,   dim3(16, 8, 4),  dim3(256), 0, stream, fsi, corr, attfq);
    hipLaunchKernelGGL(k_out,     dim3(16, 4),     dim3(256), 0, stream, fqi, attfq, out);
    hipLaunchKernelGGL(k_conv1,   dim3(64, 4),     dim3(256), 0, stream, fqi, fsi, w1, b1, x1);
    hipLaunchKernelGGL(k_conv2,   dim3(64, 4),     dim3(256), 0, stream, x1, w2, b2, x2);
    hipLaunchKernelGGL(k_pool,    dim3(400),       dim3(256), 0, stream, x2, xp);
    hipLaunchKernelGGL(k_conv3,   dim3(4),         dim3(256), 0, stream, xp, w3, b3, out);
}

// Round 4
// 909.727 us; speedup vs baseline: 2.2478x; 1.4368x over previous
//
#include <hip/hip_runtime.h>
#include <hip/hip_bf16.h>

#define DI __device__ __forceinline__

typedef short bf16x8_t __attribute__((ext_vector_type(8)));
typedef float f32x4_t __attribute__((ext_vector_type(4)));

DI unsigned short f2bf(float f) {
    unsigned u = __float_as_uint(f);
    u += 0x7fffu + ((u >> 16) & 1u);
    return (unsigned short)(u >> 16);
}

// ---------------------------------------------------------------------------
// Kernel 1: inverse channel norms for fq_feats / fs_feats (fp32).
// ---------------------------------------------------------------------------
__global__ __launch_bounds__(256) void k_norms(const float* __restrict__ fqf,
                                               const float* __restrict__ fsf,
                                               float* __restrict__ rq,
                                               float* __restrict__ rs) {
    int id = blockIdx.x * 256 + threadIdx.x;  // 0..36863
    int tensor = id / 18432;                  // block-uniform
    int r = id % 18432;
    int lb = r >> 9;
    int pp = (r & 511) * 2;
    const float* src = tensor ? fsf : fqf;
    float* dst = tensor ? rs : rq;
    const float* p = src + (size_t)lb * 524288 + pp;
    float s0 = 0.f, s1 = 0.f;
    for (int c = 0; c < 512; ++c) {
        float2 v = *(const float2*)(p + (size_t)c * 1024);
        s0 += v.x * v.x;
        s1 += v.y * v.y;
    }
    float* d = dst + lb * 1024 + pp;
    d[0] = 1.f / fmaxf(sqrtf(s0), 1e-12f);
    d[1] = 1.f / fmaxf(sqrtf(s1), 1e-12f);
}

// ---------------------------------------------------------------------------
// Kernel 2 (MFMA): corr_sum[b,q,s] = sum_l relu( dot_c(fq,fs) * rq * rs )
// (unchanged from R3 — verified)
// ---------------------------------------------------------------------------
DI void stage_tile(const float* gbase, float* lbase, int w, int lane) {
#pragma unroll
    for (int i = 0; i < 4; ++i) {
        int slot = i * 256 + w * 64 + lane;     // 16B slots 0..1023
        int r = slot >> 5;                      // row (k) 0..31
        int chp = slot & 31;                    // physical 16B chunk in row
        int msrc = ((chp * 4) - ((r >> 3) << 3)) & 127;  // un-rotated col
        __builtin_amdgcn_global_load_lds(
            (const __attribute__((address_space(1))) void*)(gbase + (size_t)r * 1024 + msrc),
            (__attribute__((address_space(3))) void*)(lbase + i * 1024 + w * 256),
            16, 0, 0);
    }
}

DI bf16x8_t build_frag(const float* base, int col, int quad) {
    const float* p = base + quad * 1024 + col;  // row quad*8, rotated col
    float f[8];
#pragma unroll
    for (int j = 0; j < 8; ++j) f[j] = p[j * 128];
    union { unsigned u[4]; bf16x8_t v; } r;
#pragma unroll
    for (int j = 0; j < 4; ++j) {
        __hip_bfloat162 h = __float22bfloat162_rn(make_float2(f[2 * j], f[2 * j + 1]));
        unsigned uu;
        __builtin_memcpy(&uu, &h, 4);
        r.u[j] = uu;
    }
    return r.v;
}

__global__ __launch_bounds__(256) void k_corr(const float* __restrict__ fqf,
                                              const float* __restrict__ fsf,
                                              const float* __restrict__ rq,
                                              const float* __restrict__ rs,
                                              float* __restrict__ corr) {
    __shared__ float As[2][4096];  // [buf][32 k x 128 m] fp32, row-rotated
    __shared__ float Bs[2][4096];
    const int b = blockIdx.z;
    const int q0 = blockIdx.y * 128;
    const int s0 = blockIdx.x * 128;
    const int t = threadIdx.x;
    const int w = t >> 6, lane = t & 63;
    const int wrow = w >> 1, wcol = w & 1;   // 2x2 waves of 64x64
    const int quad = lane >> 4, m16 = lane & 15;

    f32x4_t zero4 = {0.f, 0.f, 0.f, 0.f};
    f32x4_t master[4][4], lvl[4][4];
#pragma unroll
    for (int i = 0; i < 4; ++i)
#pragma unroll
        for (int j = 0; j < 4; ++j) { master[i][j] = zero4; lvl[i][j] = zero4; }

    {
        const float* Ab = fqf + (size_t)b * 524288 + q0;
        const float* Bb = fsf + (size_t)b * 524288 + s0;
        stage_tile(Ab, &As[0][0], w, lane);
        stage_tile(Bb, &Bs[0][0], w, lane);
    }

    for (int step = 0; step < 144; ++step) {
        const int buf = step & 1;
        __syncthreads();
        if (step < 143) {
            int ns = step + 1;
            int lb = ((ns >> 4) * 4 + b);
            int kk0 = (ns & 15) << 5;
            const float* Ab = fqf + (size_t)lb * 524288 + (size_t)kk0 * 1024 + q0;
            const float* Bb = fsf + (size_t)lb * 524288 + (size_t)kk0 * 1024 + s0;
            stage_tile(Ab, &As[buf ^ 1][0], w, lane);
            stage_tile(Bb, &Bs[buf ^ 1][0], w, lane);
        }
        const float* Ab = &As[buf][0];
        const float* Bb = &Bs[buf][0];
        bf16x8_t af[4], bfr[4];
#pragma unroll
        for (int i = 0; i < 4; ++i) {
            af[i]  = build_frag(Ab, ((wrow * 64 + i * 16 + m16) + quad * 8) & 127, quad);
            bfr[i] = build_frag(Bb, ((wcol * 64 + i * 16 + m16) + quad * 8) & 127, quad);
        }
#pragma unroll
        for (int mi = 0; mi < 4; ++mi)
#pragma unroll
            for (int ni = 0; ni < 4; ++ni)
                lvl[mi][ni] = __builtin_amdgcn_mfma_f32_16x16x32_bf16(
                    af[mi], bfr[ni], lvl[mi][ni], 0, 0, 0);

        if ((step & 15) == 15) {
            int lb = (step >> 4) * 4 + b;
            const float* rqb = rq + lb * 1024 + q0 + wrow * 64;
            const float* rsb = rs + lb * 1024 + s0 + wcol * 64;
            float rq4[4][4], rsv[4];
#pragma unroll
            for (int mi = 0; mi < 4; ++mi) {
                float4 v = *(const float4*)(rqb + mi * 16 + quad * 4);
                rq4[mi][0] = v.x; rq4[mi][1] = v.y; rq4[mi][2] = v.z; rq4[mi][3] = v.w;
            }
#pragma unroll
            for (int ni = 0; ni < 4; ++ni) rsv[ni] = rsb[ni * 16 + m16];
#pragma unroll
            for (int mi = 0; mi < 4; ++mi)
#pragma unroll
                for (int ni = 0; ni < 4; ++ni) {
#pragma unroll
                    for (int e = 0; e < 4; ++e)
                        master[mi][ni][e] += fmaxf(lvl[mi][ni][e] * rq4[mi][e] * rsv[ni], 0.f);
                    lvl[mi][ni] = zero4;
                }
        }
    }

#pragma unroll
    for (int mi = 0; mi < 4; ++mi)
#pragma unroll
        for (int e = 0; e < 4; ++e) {
            int q = q0 + wrow * 64 + mi * 16 + quad * 4 + e;
            float* cp = corr + ((size_t)(b * 1024 + q)) * 1024 + s0 + wcol * 64 + m16;
#pragma unroll
            for (int ni = 0; ni < 4; ++ni)
                cp[ni * 16] = master[mi][ni][e];
        }
}

// ---------------------------------------------------------------------------
// Kernel 3: in-place row softmax over s, scale = TEMP/9. 1 row/block.
// ---------------------------------------------------------------------------
__global__ __launch_bounds__(256) void k_softmax(float* __restrict__ corr) {
    __shared__ float red[8];
    const size_t row = blockIdx.x;
    float4* p = (float4*)(corr + (row << 10));
    const int t = threadIdx.x;
    float4 v = p[t];
    const float SC = 20.f / 9.f;
    v.x *= SC; v.y *= SC; v.z *= SC; v.w *= SC;
    float m = fmaxf(fmaxf(v.x, v.y), fmaxf(v.z, v.w));
#pragma unroll
    for (int off = 32; off >= 1; off >>= 1) m = fmaxf(m, __shfl_down(m, off));
    const int wid = t >> 6, lane = t & 63;
    if (lane == 0) red[wid] = m;
    __syncthreads();
    m = fmaxf(fmaxf(red[0], red[1]), fmaxf(red[2], red[3]));
    float e0 = __expf(v.x - m), e1 = __expf(v.y - m);
    float e2 = __expf(v.z - m), e3 = __expf(v.w - m);
    float s = e0 + e1 + e2 + e3;
#pragma unroll
    for (int off = 32; off >= 1; off >>= 1) s += __shfl_down(s, off);
    if (lane == 0) red[4 + wid] = s;
    __syncthreads();
    s = red[4] + red[5] + red[6] + red[7];
    float inv = 1.f / s;
    p[t] = make_float4(e0 * inv, e1 * inv, e2 * inv, e3 * inv);
}

// ---------------------------------------------------------------------------
// Kernel 4: att_fq[b,c,q] = sum_s attn[b,q,s] * f_s[b,c,s]  (fp32 out to ws)
// ---------------------------------------------------------------------------
__global__ __launch_bounds__(256) void k_attfq(const float* __restrict__ fsi,
                                               const float* __restrict__ attn,
                                               float* __restrict__ attfq) {
    __shared__ float As[64 * 33];  // f_s tile [c][k]
    __shared__ float Bs[64 * 33];  // attn tile [q][k]
    const int b = blockIdx.z;
    const int c0 = blockIdx.y * 64;
    const int q0 = blockIdx.x * 64;
    const int t = threadIdx.x;
    const int ty = t >> 4, tx = t & 15;
    const int srow = t >> 2, sk = (t & 3) * 8;
    const float* Ag = fsi + (((size_t)(b * 512 + c0 + srow)) << 10) + sk;
    const float* Bg = attn + (((size_t)(b * 1024 + q0 + srow)) << 10) + sk;
    float acc[4][4] = {};
    for (int s0 = 0; s0 < 1024; s0 += 32) {
        float4 a0 = *(const float4*)(Ag + s0);
        float4 a1 = *(const float4*)(Ag + s0 + 4);
        float4 b0 = *(const float4*)(Bg + s0);
        float4 b1 = *(const float4*)(Bg + s0 + 4);
        __syncthreads();
        float* ap = &As[srow * 33 + sk];
        ap[0] = a0.x; ap[1] = a0.y; ap[2] = a0.z; ap[3] = a0.w;
        ap[4] = a1.x; ap[5] = a1.y; ap[6] = a1.z; ap[7] = a1.w;
        float* bp = &Bs[srow * 33 + sk];
        bp[0] = b0.x; bp[1] = b0.y; bp[2] = b0.z; bp[3] = b0.w;
        bp[4] = b1.x; bp[5] = b1.y; bp[6] = b1.z; bp[7] = b1.w;
        __syncthreads();
#pragma unroll
        for (int k = 0; k < 32; ++k) {
            float ar[4], br[4];
#pragma unroll
            for (int i = 0; i < 4; ++i) ar[i] = As[(ty * 4 + i) * 33 + k];
#pragma unroll
            for (int j = 0; j < 4; ++j) br[j] = Bs[(tx * 4 + j) * 33 + k];
#pragma unroll
            for (int i = 0; i < 4; ++i)
#pragma unroll
                for (int j = 0; j < 4; ++j)
                    acc[i][j] = fmaf(ar[i], br[j], acc[i][j]);
        }
    }
#pragma unroll
    for (int i = 0; i < 4; ++i) {
        float* op = attfq + (((size_t)(b * 512 + c0 + ty * 4 + i)) << 10) + q0 + tx * 4;
        *(float4*)op = make_float4(acc[i][0], acc[i][1], acc[i][2], acc[i][3]);
    }
}

// ---------------------------------------------------------------------------
// Kernel 5: fq = l2n(f_q,C) + 0.5*l2n(att_fq,C); write fq & att_fq (fp32).
// ---------------------------------------------------------------------------
__global__ __launch_bounds__(256) void k_out(const float* __restrict__ fqi,
                                             const float* __restrict__ attfq,
                                             float* __restrict__ out) {
    __shared__ float redq[256], reda[256];
    __shared__ float rnq[64], rna[64];
    const int b = blockIdx.y;
    const int p0 = blockIdx.x * 64;
    const int t = threadIdx.x;
    const int pl = t & 63, cg = t >> 6;
    const int pos = p0 + pl;
    const float* qp = fqi + (((size_t)b) << 19) + pos;
    const float* ap = attfq + (((size_t)b) << 19) + pos;
    float sq = 0.f, sa = 0.f;
    for (int c = cg * 128; c < cg * 128 + 128; ++c) {
        float q = qp[(size_t)c << 10];
        float a = ap[(size_t)c << 10];
        sq += q * q;
        sa += a * a;
    }
    redq[t] = sq; reda[t] = sa;
    __syncthreads();
    if (t < 64) {
        float q = redq[t] + redq[t + 64] + redq[t + 128] + redq[t + 192];
        float a = reda[t] + reda[t + 64] + reda[t + 128] + reda[t + 192];
        rnq[t] = 1.f / fmaxf(sqrtf(q), 1e-12f);
        rna[t] = 1.f / fmaxf(sqrtf(a), 1e-12f);
    }
    __syncthreads();
    const float RQ = rnq[pl], RA = 0.5f * rna[pl];
    float* o1 = out + (((size_t)b) << 19) + pos;
    float* o2 = o1 + 2097152;
    for (int c = cg * 128; c < cg * 128 + 128; ++c) {
        float q = qp[(size_t)c << 10];
        float a = ap[(size_t)c << 10];
        o1[(size_t)c << 10] = q * RQ + a * RA;
        o2[(size_t)c << 10] = a;
    }
}

// ---------------------------------------------------------------------------
// Kernel 6a: pack w1 fp32 [256 oc][1024 ic][9 tap] -> bf16 [tap][s][oc][36]
// (36-slot rows = 72B stride; slots 32..35 zero pad for LDS bank spread)
// ---------------------------------------------------------------------------
__global__ __launch_bounds__(256) void k_w1pack(const float* __restrict__ w1,
                                                unsigned short* __restrict__ w1p) {
    int pid = blockIdx.x * 256 + threadIdx.x;  // 0..262143 = (oc,ic)
    int oc = pid >> 10, ic = pid & 1023;
    const float* src = w1 + (size_t)pid * 9;
    float f[9];
#pragma unroll
    for (int tp = 0; tp < 9; ++tp) f[tp] = src[tp];
    int s = ic >> 5, j = ic & 31;
#pragma unroll
    for (int tp = 0; tp < 9; ++tp) {
        size_t row = ((size_t)(tp * 32 + s) * 256 + oc) * 36;
        w1p[row + j] = f2bf(f[tp]);
        if (j < 4) w1p[row + 32 + j] = 0;
    }
}

// ---------------------------------------------------------------------------
// Kernel 6b (MFMA): conv1 partials per kh-group.
// P[khg][b][oc 256][pos 1024] = sum_{kw,ic} w1[oc][ic][khg][kw] * in_shift
// Block: M=256 oc x N=64 pos, K = 3 kw x 1024 ic (96 steps of BK=32).
// A: packed bf16 [oc][36] rows staged via global_load_lds; frag = 2x ds_read_b64.
// B: masked float2 loads of shifted input, k_corr-style rotated [k][64] fp32.
// ---------------------------------------------------------------------------
__global__ __launch_bounds__(256) void k_conv1m(const float* __restrict__ fqi,
                                                const float* __restrict__ fsi,
                                                const unsigned short* __restrict__ w1p,
                                                float* __restrict__ P) {
    __shared__ __align__(16) char As[2][18432];   // [buf][256 oc][36 bf16]
    __shared__ float Bs[2][2048];                 // [buf][32 k][64 n] rotated
    const int p0 = blockIdx.x * 64;
    const int b = blockIdx.y;
    const int khg = blockIdx.z;
    const int dy = 2 * khg - 2;
    const int t = threadIdx.x;
    const int w = t >> 6, lane = t & 63;
    const int quad = lane >> 4, m16 = lane & 15;
    const int krow = t >> 3, n0 = (t & 7) * 8;   // B-staging coords
    const int brot = (krow >> 3) * 8;

    f32x4_t acc[4][4];
#pragma unroll
    for (int i = 0; i < 4; ++i)
#pragma unroll
        for (int j = 0; j < 4; ++j) acc[i][j] = (f32x4_t){0.f, 0.f, 0.f, 0.f};

    // --- staging lambdas ---
    auto stageA = [&](int f, int buf) {
        int kw = f >> 5, s = f & 31;
        const char* src = (const char*)(w1p + (size_t)((khg * 3 + kw) * 32 + s) * 9216);
#pragma unroll
        for (int i = 0; i < 5; ++i) {
            int idx = i * 4 + w;
            if (idx < 18)
                __builtin_amdgcn_global_load_lds(
                    (const __attribute__((address_space(1))) void*)(src + idx * 1024 + lane * 16),
                    (__attribute__((address_space(3))) void*)(&As[buf][0] + idx * 1024),
                    16, 0, 0);
        }
    };
    auto stageB = [&](int f, int buf) {
        int kw = f >> 5, s = f & 31;
        int dx = 2 * kw - 2;
        int off = dy * 32 + dx;
        int ch = s * 32 + krow;
        const float* plane = (ch < 512)
            ? (fqi + (((size_t)(b * 512 + ch)) << 10))
            : (fsi + (((size_t)(b * 512 + ch - 512)) << 10));
        float* dst = &Bs[buf][krow * 64 + ((n0 + brot) & 63)];
#pragma unroll
        for (int j2 = 0; j2 < 4; ++j2) {
            int e0 = p0 + n0 + 2 * j2;
            int ba = e0 + off;
            int c = min(max(ba, 0), 1022);
            float2 v = *(const float2*)(plane + c);
            int y0 = e0 >> 5, xg0 = e0 & 31;
            int y1 = (e0 + 1) >> 5, xg1 = (e0 + 1) & 31;
            bool v0 = ((unsigned)(y0 + dy) < 32u) && ((unsigned)(xg0 + dx) < 32u);
            bool v1 = ((unsigned)(y1 + dy) < 32u) && ((unsigned)(xg1 + dx) < 32u);
            float2 o;
            o.x = v0 ? v.x : 0.f;
            o.y = v1 ? v.y : 0.f;
            *(float2*)(dst + 2 * j2) = o;
        }
    };

    stageA(0, 0);
    stageB(0, 0);

    for (int f = 0; f < 96; ++f) {
        const int buf = f & 1;
        __syncthreads();
        if (f < 95) {
            stageA(f + 1, buf ^ 1);
            stageB(f + 1, buf ^ 1);
        }
        // A frags: oc = w*64 + i*16 + m16, k = quad*8 + j (contiguous in row)
        bf16x8_t af[4], bfr[4];
#pragma unroll
        for (int i = 0; i < 4; ++i) {
            const char* ap = &As[buf][0] + (size_t)(w * 64 + i * 16 + m16) * 72 + quad * 16;
            union { unsigned long long d[2]; bf16x8_t v; } u;
            u.d[0] = *(const unsigned long long*)ap;
            u.d[1] = *(const unsigned long long*)(ap + 8);
            af[i] = u.v;
        }
        // B frags: n = i*16 + m16 (rotated), k = quad*8 + j
#pragma unroll
        for (int i = 0; i < 4; ++i) {
            const float* p = &Bs[buf][0] + quad * 512 + (((i * 16 + m16) + quad * 8) & 63);
            float fv[8];
#pragma unroll
            for (int j = 0; j < 8; ++j) fv[j] = p[j * 64];
            union { unsigned u[4]; bf16x8_t v; } r;
#pragma unroll
            for (int j = 0; j < 4; ++j) {
                __hip_bfloat162 h = __float22bfloat162_rn(make_float2(fv[2 * j], fv[2 * j + 1]));
                unsigned uu;
                __builtin_memcpy(&uu, &h, 4);
                r.u[j] = uu;
            }
            bfr[i] = r.v;
        }
#pragma unroll
        for (int mi = 0; mi < 4; ++mi)
#pragma unroll
            for (int ni = 0; ni < 4; ++ni)
                acc[mi][ni] = __builtin_amdgcn_mfma_f32_16x16x32_bf16(
                    af[mi], bfr[ni], acc[mi][ni], 0, 0, 0);
    }

    float* Pb = P + (((size_t)(khg * 4 + b)) << 18) + p0;
#pragma unroll
    for (int mi = 0; mi < 4; ++mi)
#pragma unroll
        for (int e = 0; e < 4; ++e) {
            int oc = w * 64 + mi * 16 + quad * 4 + e;
            float* row = Pb + (size_t)oc * 1024 + m16;
#pragma unroll
            for (int ni = 0; ni < 4; ++ni)
                row[ni * 16] = acc[mi][ni][e];
        }
}

// ---------------------------------------------------------------------------
// Kernel 6c: x1 = relu(P0+P1+P2 + b1)
// ---------------------------------------------------------------------------
__global__ __launch_bounds__(256) void k_c1comb(const float* __restrict__ P,
                                                const float* __restrict__ b1,
                                                float* __restrict__ x1) {
    int id = blockIdx.x * 256 + threadIdx.x;  // float4 index, 0..262143
    int oc = (id >> 8) & 255;
    const float4* P4 = (const float4*)P;
    float4 a = P4[id];
    float4 bv = P4[id + 262144];
    float4 c = P4[id + 524288];
    float bb = b1[oc];
    float4 o;
    o.x = fmaxf(a.x + bv.x + c.x + bb, 0.f);
    o.y = fmaxf(a.y + bv.y + c.y + bb, 0.f);
    o.z = fmaxf(a.z + bv.z + c.z + bb, 0.f);
    o.w = fmaxf(a.w + bv.w + c.w + bb, 0.f);
    ((float4*)x1)[id] = o;
}

// ---------------------------------------------------------------------------
// Kernel 7: conv2 3x3 valid on x1 [256ch,32,32] -> x2 [256,30,30] (no relu)
// ---------------------------------------------------------------------------
__global__ __launch_bounds__(256) void k_conv2(const float* __restrict__ x1,
                                               const float* __restrict__ w2,
                                               const float* __restrict__ b2,
                                               float* __restrict__ x2) {
    __shared__ float in_lds[4 * 1024];
    __shared__ float w_lds[144];
    const int b = blockIdx.y;
    const int oc0 = blockIdx.x * 4;
    const int t = threadIdx.x;
    int py[4], px[4];
    bool valid[4];
#pragma unroll
    for (int j = 0; j < 4; ++j) {
        int p = t + j * 256;
        valid[j] = p < 900;
        if (valid[j]) { py[j] = p / 30; px[j] = p % 30; }
        else { py[j] = 0; px[j] = 0; }
    }
    float acc[4][4];
#pragma unroll
    for (int oi = 0; oi < 4; ++oi) {
        float bb = b2[oc0 + oi];
#pragma unroll
        for (int j = 0; j < 4; ++j) acc[oi][j] = bb;
    }
    for (int ic0 = 0; ic0 < 256; ic0 += 4) {
        float4 gv[4];
#pragma unroll
        for (int i = 0; i < 4; ++i) {
            int idx4 = i * 256 + t;
            int icc = idx4 >> 8;
            int pos4 = (idx4 & 255) * 4;
            gv[i] = *(const float4*)(x1 + (((size_t)(b * 256 + ic0 + icc)) << 10) + pos4);
        }
        float wreg = 0.f;
        if (t < 144) {
            int oi = t / 36, rem = t % 36;
            wreg = w2[((size_t)(oc0 + oi) * 256 + ic0 + rem / 9) * 9 + rem % 9];
        }
        __syncthreads();
#pragma unroll
        for (int i = 0; i < 4; ++i) {
            int idx4 = i * 256 + t;
            int icc = idx4 >> 8;
            int pos4 = (idx4 & 255) * 4;
            *(float4*)&in_lds[icc * 1024 + pos4] = gv[i];
        }
        if (t < 144) w_lds[t] = wreg;
        __syncthreads();
#pragma unroll
        for (int icc = 0; icc < 4; ++icc) {
            float wv[9][4];
#pragma unroll
            for (int oi = 0; oi < 4; ++oi)
#pragma unroll
                for (int tp = 0; tp < 9; ++tp)
                    wv[tp][oi] = w_lds[oi * 36 + icc * 9 + tp];
#pragma unroll
            for (int kh = 0; kh < 3; ++kh)
#pragma unroll
                for (int kw = 0; kw < 3; ++kw)
#pragma unroll
                    for (int j = 0; j < 4; ++j) {
                        float iv = in_lds[icc * 1024 + (py[j] + kh) * 32 + px[j] + kw];
#pragma unroll
                        for (int oi = 0; oi < 4; ++oi)
                            acc[oi][j] = fmaf(wv[kh * 3 + kw][oi], iv, acc[oi][j]);
                    }
        }
        __syncthreads();
    }
#pragma unroll
    for (int j = 0; j < 4; ++j)
        if (valid[j])
#pragma unroll
            for (int oi = 0; oi < 4; ++oi)
                x2[((size_t)(b * 256 + oc0 + oi)) * 900 + t + j * 256] = acc[oi][j];
}

// ---------------------------------------------------------------------------
// Kernel 8: 3x3/3 maxpool (30x30 -> 10x10)
// ---------------------------------------------------------------------------
__global__ __launch_bounds__(256) void k_pool(const float* __restrict__ x2,
                                              float* __restrict__ xp) {
    int id = blockIdx.x * 256 + threadIdx.x;
    if (id >= 102400) return;
    int px = id % 10;
    int tmp = id / 10;
    int py = tmp % 10;
    int ch = tmp / 10;
    const float* ip = x2 + (size_t)ch * 900 + (3 * py) * 30 + 3 * px;
    float m = ip[0];
#pragma unroll
    for (int dy = 0; dy < 3; ++dy)
#pragma unroll
        for (int dx = 0; dx < 3; ++dx) m = fmaxf(m, ip[dy * 30 + dx]);
    xp[id] = m;
}

// ---------------------------------------------------------------------------
// Kernel 9: conv3 (256ch, 10x10 -> 8x8) + spatial mean + b3 -> weight[1,B]
// ---------------------------------------------------------------------------
__global__ __launch_bounds__(256) void k_conv3(const float* __restrict__ xp,
                                               const float* __restrict__ w3,
                                               const float* __restrict__ b3,
                                               float* __restrict__ out) {
    __shared__ float s[256];
    int b = blockIdx.x, t = threadIdx.x;
    int pos = t & 63, qi = t >> 6;
    int y = pos >> 3, x = pos & 7;
    float acc = 0.f;
    for (int ic = qi * 64; ic < qi * 64 + 64; ++ic) {
        const float* ip = xp + ((size_t)(b * 256 + ic)) * 100 + y * 10 + x;
#pragma unroll
        for (int kh = 0; kh < 3; ++kh)
#pragma unroll
            for (int kw = 0; kw < 3; ++kw)
                acc = fmaf(w3[ic * 9 + kh * 3 + kw], ip[kh * 10 + kw], acc);
    }
    s[t] = acc;
    __syncthreads();
    if (t < 64) {
        float v = s[t] + s[t + 64] + s[t + 128] + s[t + 192];
#pragma unroll
        for (int off = 32; off >= 1; off >>= 1) v += __shfl_down(v, off);
        if (t == 0) out[4194304 + b] = v * (1.f / 64.f) + b3[0];
    }
}

// ---------------------------------------------------------------------------
extern "C" void kernel_launch(void* const* d_in, const int* in_sizes, int n_in,
                              void* d_out, int out_size, void* d_ws, size_t ws_size,
                              hipStream_t stream) {
    (void)in_sizes; (void)n_in; (void)out_size; (void)ws_size;
    const float* fqf = (const float*)d_in[0];  // fq_feats [9,4,512,32,32]
    const float* fsf = (const float*)d_in[1];  // fs_feats
    const float* fqi = (const float*)d_in[2];  // f_q [4,512,32,32]
    const float* fsi = (const float*)d_in[3];  // f_s
    const float* w1  = (const float*)d_in[4];
    const float* b1  = (const float*)d_in[5];
    const float* w2  = (const float*)d_in[6];
    const float* b2  = (const float*)d_in[7];
    const float* w3  = (const float*)d_in[8];
    const float* b3  = (const float*)d_in[9];
    float* out = (float*)d_out;

    float* W = (float*)d_ws;
    // Phase 1 (conv1): P [0 .. 3,145,728), w1p bf16 [3,145,728 .. 4,472,832)
    float* P = W;
    unsigned short* w1p = (unsigned short*)(W + 3145728);
    // Phase 2 (attention): aliases phase-1 region (lifetimes disjoint)
    float* corr  = W;              // 4,194,304 f32, reused as attn
    float* rq    = W + 4194304;    //    36,864
    float* rs    = W + 4231168;    //    36,864
    float* attfq = W + 4268032;    // 2,097,152 (ends 6,365,184)
    // Persistent conv outputs (no overlap with either phase scratch)
    float* x1    = W + 6365184;    // 1,048,576
    float* x2    = W + 7413760;    //   921,600
    float* xp    = W + 8335360;    //   102,400  (end 8,437,760 f32 = 33.8 MB)

    // conv1 first (its scratch dies before corr is written)
    hipLaunchKernelGGL(k_w1pack,  dim3(1024),      dim3(256), 0, stream, w1, w1p);
    hipLaunchKernelGGL(k_conv1m,  dim3(16, 4, 3),  dim3(256), 0, stream, fqi, fsi, w1p, P);
    hipLaunchKernelGGL(k_c1comb,  dim3(1024),      dim3(256), 0, stream, P, b1, x1);
    // attention path
    hipLaunchKernelGGL(k_norms,   dim3(144),       dim3(256), 0, stream, fqf, fsf, rq, rs);
    hipLaunchKernelGGL(k_corr,    dim3(8, 8, 4),   dim3(256), 0, stream, fqf, fsf, rq, rs, corr);
    hipLaunchKernelGGL(k_softmax, dim3(4096),      dim3(256), 0, stream, corr);
    hipLaunchKernelGGL(k_attfq,   dim3(16, 8, 4),  dim3(256), 0, stream, fsi, corr, attfq);
    hipLaunchKernelGGL(k_out,     dim3(16, 4),     dim3(256), 0, stream, fqi, attfq, out);
    // conv tail
    hipLaunchKernelGGL(k_conv2,   dim3(64, 4),     dim3(256), 0, stream, x1, w2, b2, x2);
    hipLaunchKernelGGL(k_pool,    dim3(400),       dim3(256), 0, stream, x2, xp);
    hipLaunchKernelGGL(k_conv3,   dim3(4),         dim3(256), 0, stream, xp, w3, b3, out);
}

// Round 5
// 718.228 us; speedup vs baseline: 2.8471x; 1.2666x over previous
//
#include <hip/hip_runtime.h>
#include <hip/hip_bf16.h>

#define DI __device__ __forceinline__

typedef short bf16x8_t __attribute__((ext_vector_type(8)));
typedef float f32x4_t __attribute__((ext_vector_type(4)));

DI unsigned short f2bf(float f) {
    unsigned u = __float_as_uint(f);
    u += 0x7fffu + ((u >> 16) & 1u);
    return (unsigned short)(u >> 16);
}

// ---------------------------------------------------------------------------
// Kernel 1: inverse channel norms for fq_feats / fs_feats (fp32).
// ---------------------------------------------------------------------------
__global__ __launch_bounds__(256) void k_norms(const float* __restrict__ fqf,
                                               const float* __restrict__ fsf,
                                               float* __restrict__ rq,
                                               float* __restrict__ rs) {
    int id = blockIdx.x * 256 + threadIdx.x;  // 0..36863
    int tensor = id / 18432;                  // block-uniform
    int r = id % 18432;
    int lb = r >> 9;
    int pp = (r & 511) * 2;
    const float* src = tensor ? fsf : fqf;
    float* dst = tensor ? rs : rq;
    const float* p = src + (size_t)lb * 524288 + pp;
    float s0 = 0.f, s1 = 0.f;
    for (int c = 0; c < 512; ++c) {
        float2 v = *(const float2*)(p + (size_t)c * 1024);
        s0 += v.x * v.x;
        s1 += v.y * v.y;
    }
    float* d = dst + lb * 1024 + pp;
    d[0] = 1.f / fmaxf(sqrtf(s0), 1e-12f);
    d[1] = 1.f / fmaxf(sqrtf(s1), 1e-12f);
}

// ---------------------------------------------------------------------------
// Kernel 2 (MFMA): corr_sum[b,q,s] = sum_l relu( dot_c(fq,fs) * rq * rs )
// (verified)
// ---------------------------------------------------------------------------
DI void stage_tile(const float* gbase, float* lbase, int w, int lane) {
#pragma unroll
    for (int i = 0; i < 4; ++i) {
        int slot = i * 256 + w * 64 + lane;     // 16B slots 0..1023
        int r = slot >> 5;                      // row (k) 0..31
        int chp = slot & 31;                    // physical 16B chunk in row
        int msrc = ((chp * 4) - ((r >> 3) << 3)) & 127;  // un-rotated col
        __builtin_amdgcn_global_load_lds(
            (const __attribute__((address_space(1))) void*)(gbase + (size_t)r * 1024 + msrc),
            (__attribute__((address_space(3))) void*)(lbase + i * 1024 + w * 256),
            16, 0, 0);
    }
}

DI bf16x8_t build_frag(const float* base, int col, int quad) {
    const float* p = base + quad * 1024 + col;  // row quad*8, rotated col
    float f[8];
#pragma unroll
    for (int j = 0; j < 8; ++j) f[j] = p[j * 128];
    union { unsigned u[4]; bf16x8_t v; } r;
#pragma unroll
    for (int j = 0; j < 4; ++j) {
        __hip_bfloat162 h = __float22bfloat162_rn(make_float2(f[2 * j], f[2 * j + 1]));
        unsigned uu;
        __builtin_memcpy(&uu, &h, 4);
        r.u[j] = uu;
    }
    return r.v;
}

__global__ __launch_bounds__(256) void k_corr(const float* __restrict__ fqf,
                                              const float* __restrict__ fsf,
                                              const float* __restrict__ rq,
                                              const float* __restrict__ rs,
                                              float* __restrict__ corr) {
    __shared__ float As[2][4096];  // [buf][32 k x 128 m] fp32, row-rotated
    __shared__ float Bs[2][4096];
    const int b = blockIdx.z;
    const int q0 = blockIdx.y * 128;
    const int s0 = blockIdx.x * 128;
    const int t = threadIdx.x;
    const int w = t >> 6, lane = t & 63;
    const int wrow = w >> 1, wcol = w & 1;   // 2x2 waves of 64x64
    const int quad = lane >> 4, m16 = lane & 15;

    f32x4_t zero4 = {0.f, 0.f, 0.f, 0.f};
    f32x4_t master[4][4], lvl[4][4];
#pragma unroll
    for (int i = 0; i < 4; ++i)
#pragma unroll
        for (int j = 0; j < 4; ++j) { master[i][j] = zero4; lvl[i][j] = zero4; }

    {
        const float* Ab = fqf + (size_t)b * 524288 + q0;
        const float* Bb = fsf + (size_t)b * 524288 + s0;
        stage_tile(Ab, &As[0][0], w, lane);
        stage_tile(Bb, &Bs[0][0], w, lane);
    }

    for (int step = 0; step < 144; ++step) {
        const int buf = step & 1;
        __syncthreads();
        if (step < 143) {
            int ns = step + 1;
            int lb = ((ns >> 4) * 4 + b);
            int kk0 = (ns & 15) << 5;
            const float* Ab = fqf + (size_t)lb * 524288 + (size_t)kk0 * 1024 + q0;
            const float* Bb = fsf + (size_t)lb * 524288 + (size_t)kk0 * 1024 + s0;
            stage_tile(Ab, &As[buf ^ 1][0], w, lane);
            stage_tile(Bb, &Bs[buf ^ 1][0], w, lane);
        }
        const float* Ab = &As[buf][0];
        const float* Bb = &Bs[buf][0];
        bf16x8_t af[4], bfr[4];
#pragma unroll
        for (int i = 0; i < 4; ++i) {
            af[i]  = build_frag(Ab, ((wrow * 64 + i * 16 + m16) + quad * 8) & 127, quad);
            bfr[i] = build_frag(Bb, ((wcol * 64 + i * 16 + m16) + quad * 8) & 127, quad);
        }
#pragma unroll
        for (int mi = 0; mi < 4; ++mi)
#pragma unroll
            for (int ni = 0; ni < 4; ++ni)
                lvl[mi][ni] = __builtin_amdgcn_mfma_f32_16x16x32_bf16(
                    af[mi], bfr[ni], lvl[mi][ni], 0, 0, 0);

        if ((step & 15) == 15) {
            int lb = (step >> 4) * 4 + b;
            const float* rqb = rq + lb * 1024 + q0 + wrow * 64;
            const float* rsb = rs + lb * 1024 + s0 + wcol * 64;
            float rq4[4][4], rsv[4];
#pragma unroll
            for (int mi = 0; mi < 4; ++mi) {
                float4 v = *(const float4*)(rqb + mi * 16 + quad * 4);
                rq4[mi][0] = v.x; rq4[mi][1] = v.y; rq4[mi][2] = v.z; rq4[mi][3] = v.w;
            }
#pragma unroll
            for (int ni = 0; ni < 4; ++ni) rsv[ni] = rsb[ni * 16 + m16];
#pragma unroll
            for (int mi = 0; mi < 4; ++mi)
#pragma unroll
                for (int ni = 0; ni < 4; ++ni) {
#pragma unroll
                    for (int e = 0; e < 4; ++e)
                        master[mi][ni][e] += fmaxf(lvl[mi][ni][e] * rq4[mi][e] * rsv[ni], 0.f);
                    lvl[mi][ni] = zero4;
                }
        }
    }

#pragma unroll
    for (int mi = 0; mi < 4; ++mi)
#pragma unroll
        for (int e = 0; e < 4; ++e) {
            int q = q0 + wrow * 64 + mi * 16 + quad * 4 + e;
            float* cp = corr + ((size_t)(b * 1024 + q)) * 1024 + s0 + wcol * 64 + m16;
#pragma unroll
            for (int ni = 0; ni < 4; ++ni)
                cp[ni * 16] = master[mi][ni][e];
        }
}

// ---------------------------------------------------------------------------
// Kernel 3: in-place row softmax over s, scale = TEMP/9. 1 row/block.
// ---------------------------------------------------------------------------
__global__ __launch_bounds__(256) void k_softmax(float* __restrict__ corr) {
    __shared__ float red[8];
    const size_t row = blockIdx.x;
    float4* p = (float4*)(corr + (row << 10));
    const int t = threadIdx.x;
    float4 v = p[t];
    const float SC = 20.f / 9.f;
    v.x *= SC; v.y *= SC; v.z *= SC; v.w *= SC;
    float m = fmaxf(fmaxf(v.x, v.y), fmaxf(v.z, v.w));
#pragma unroll
    for (int off = 32; off >= 1; off >>= 1) m = fmaxf(m, __shfl_down(m, off));
    const int wid = t >> 6, lane = t & 63;
    if (lane == 0) red[wid] = m;
    __syncthreads();
    m = fmaxf(fmaxf(red[0], red[1]), fmaxf(red[2], red[3]));
    float e0 = __expf(v.x - m), e1 = __expf(v.y - m);
    float e2 = __expf(v.z - m), e3 = __expf(v.w - m);
    float s = e0 + e1 + e2 + e3;
#pragma unroll
    for (int off = 32; off >= 1; off >>= 1) s += __shfl_down(s, off);
    if (lane == 0) red[4 + wid] = s;
    __syncthreads();
    s = red[4] + red[5] + red[6] + red[7];
    float inv = 1.f / s;
    p[t] = make_float4(e0 * inv, e1 * inv, e2 * inv, e3 * inv);
}

// ---------------------------------------------------------------------------
// Kernel 4: att_fq[b,c,q] = sum_s attn[b,q,s] * f_s[b,c,s]  (fp32 out to ws)
// ---------------------------------------------------------------------------
__global__ __launch_bounds__(256) void k_attfq(const float* __restrict__ fsi,
                                               const float* __restrict__ attn,
                                               float* __restrict__ attfq) {
    __shared__ float As[64 * 33];  // f_s tile [c][k]
    __shared__ float Bs[64 * 33];  // attn tile [q][k]
    const int b = blockIdx.z;
    const int c0 = blockIdx.y * 64;
    const int q0 = blockIdx.x * 64;
    const int t = threadIdx.x;
    const int ty = t >> 4, tx = t & 15;
    const int srow = t >> 2, sk = (t & 3) * 8;
    const float* Ag = fsi + (((size_t)(b * 512 + c0 + srow)) << 10) + sk;
    const float* Bg = attn + (((size_t)(b * 1024 + q0 + srow)) << 10) + sk;
    float acc[4][4] = {};
    for (int s0 = 0; s0 < 1024; s0 += 32) {
        float4 a0 = *(const float4*)(Ag + s0);
        float4 a1 = *(const float4*)(Ag + s0 + 4);
        float4 b0 = *(const float4*)(Bg + s0);
        float4 b1 = *(const float4*)(Bg + s0 + 4);
        __syncthreads();
        float* ap = &As[srow * 33 + sk];
        ap[0] = a0.x; ap[1] = a0.y; ap[2] = a0.z; ap[3] = a0.w;
        ap[4] = a1.x; ap[5] = a1.y; ap[6] = a1.z; ap[7] = a1.w;
        float* bp = &Bs[srow * 33 + sk];
        bp[0] = b0.x; bp[1] = b0.y; bp[2] = b0.z; bp[3] = b0.w;
        bp[4] = b1.x; bp[5] = b1.y; bp[6] = b1.z; bp[7] = b1.w;
        __syncthreads();
#pragma unroll
        for (int k = 0; k < 32; ++k) {
            float ar[4], br[4];
#pragma unroll
            for (int i = 0; i < 4; ++i) ar[i] = As[(ty * 4 + i) * 33 + k];
#pragma unroll
            for (int j = 0; j < 4; ++j) br[j] = Bs[(tx * 4 + j) * 33 + k];
#pragma unroll
            for (int i = 0; i < 4; ++i)
#pragma unroll
                for (int j = 0; j < 4; ++j)
                    acc[i][j] = fmaf(ar[i], br[j], acc[i][j]);
        }
    }
#pragma unroll
    for (int i = 0; i < 4; ++i) {
        float* op = attfq + (((size_t)(b * 512 + c0 + ty * 4 + i)) << 10) + q0 + tx * 4;
        *(float4*)op = make_float4(acc[i][0], acc[i][1], acc[i][2], acc[i][3]);
    }
}

// ---------------------------------------------------------------------------
// Kernel 5: fq = l2n(f_q,C) + 0.5*l2n(att_fq,C); write fq & att_fq (fp32).
// ---------------------------------------------------------------------------
__global__ __launch_bounds__(256) void k_out(const float* __restrict__ fqi,
                                             const float* __restrict__ attfq,
                                             float* __restrict__ out) {
    __shared__ float redq[256], reda[256];
    __shared__ float rnq[64], rna[64];
    const int b = blockIdx.y;
    const int p0 = blockIdx.x * 64;
    const int t = threadIdx.x;
    const int pl = t & 63, cg = t >> 6;
    const int pos = p0 + pl;
    const float* qp = fqi + (((size_t)b) << 19) + pos;
    const float* ap = attfq + (((size_t)b) << 19) + pos;
    float sq = 0.f, sa = 0.f;
    for (int c = cg * 128; c < cg * 128 + 128; ++c) {
        float q = qp[(size_t)c << 10];
        float a = ap[(size_t)c << 10];
        sq += q * q;
        sa += a * a;
    }
    redq[t] = sq; reda[t] = sa;
    __syncthreads();
    if (t < 64) {
        float q = redq[t] + redq[t + 64] + redq[t + 128] + redq[t + 192];
        float a = reda[t] + reda[t + 64] + reda[t + 128] + reda[t + 192];
        rnq[t] = 1.f / fmaxf(sqrtf(q), 1e-12f);
        rna[t] = 1.f / fmaxf(sqrtf(a), 1e-12f);
    }
    __syncthreads();
    const float RQ = rnq[pl], RA = 0.5f * rna[pl];
    float* o1 = out + (((size_t)b) << 19) + pos;
    float* o2 = o1 + 2097152;
    for (int c = cg * 128; c < cg * 128 + 128; ++c) {
        float q = qp[(size_t)c << 10];
        float a = ap[(size_t)c << 10];
        o1[(size_t)c << 10] = q * RQ + a * RA;
        o2[(size_t)c << 10] = a;
    }
}

// ---------------------------------------------------------------------------
// Kernel 6a: pack w1 fp32 [256 oc][1024 ic][9 tap] -> bf16 [tap][s][oc][36]
// ---------------------------------------------------------------------------
__global__ __launch_bounds__(256) void k_w1pack(const float* __restrict__ w1,
                                                unsigned short* __restrict__ w1p) {
    int pid = blockIdx.x * 256 + threadIdx.x;  // 0..262143 = (oc,ic)
    int oc = pid >> 10, ic = pid & 1023;
    const float* src = w1 + (size_t)pid * 9;
    float f[9];
#pragma unroll
    for (int tp = 0; tp < 9; ++tp) f[tp] = src[tp];
    int s = ic >> 5, j = ic & 31;
#pragma unroll
    for (int tp = 0; tp < 9; ++tp) {
        size_t row = ((size_t)(tp * 32 + s) * 256 + oc) * 36;
        w1p[row + j] = f2bf(f[tp]);
        if (j < 4) w1p[row + 32 + j] = 0;
    }
}

// ---------------------------------------------------------------------------
// Kernel 6b (MFMA): conv1 partials per kh-group. (verified)
// ---------------------------------------------------------------------------
__global__ __launch_bounds__(256) void k_conv1m(const float* __restrict__ fqi,
                                                const float* __restrict__ fsi,
                                                const unsigned short* __restrict__ w1p,
                                                float* __restrict__ P) {
    __shared__ __align__(16) char As[2][18432];   // [buf][256 oc][36 bf16]
    __shared__ float Bs[2][2048];                 // [buf][32 k][64 n] rotated
    const int p0 = blockIdx.x * 64;
    const int b = blockIdx.y;
    const int khg = blockIdx.z;
    const int dy = 2 * khg - 2;
    const int t = threadIdx.x;
    const int w = t >> 6, lane = t & 63;
    const int quad = lane >> 4, m16 = lane & 15;
    const int krow = t >> 3, n0 = (t & 7) * 8;   // B-staging coords
    const int brot = (krow >> 3) * 8;

    f32x4_t acc[4][4];
#pragma unroll
    for (int i = 0; i < 4; ++i)
#pragma unroll
        for (int j = 0; j < 4; ++j) acc[i][j] = (f32x4_t){0.f, 0.f, 0.f, 0.f};

    auto stageA = [&](int f, int buf) {
        int kw = f >> 5, s = f & 31;
        const char* src = (const char*)(w1p + (size_t)((khg * 3 + kw) * 32 + s) * 9216);
#pragma unroll
        for (int i = 0; i < 5; ++i) {
            int idx = i * 4 + w;
            if (idx < 18)
                __builtin_amdgcn_global_load_lds(
                    (const __attribute__((address_space(1))) void*)(src + idx * 1024 + lane * 16),
                    (__attribute__((address_space(3))) void*)(&As[buf][0] + idx * 1024),
                    16, 0, 0);
        }
    };
    auto stageB = [&](int f, int buf) {
        int kw = f >> 5, s = f & 31;
        int dx = 2 * kw - 2;
        int off = dy * 32 + dx;
        int ch = s * 32 + krow;
        const float* plane = (ch < 512)
            ? (fqi + (((size_t)(b * 512 + ch)) << 10))
            : (fsi + (((size_t)(b * 512 + ch - 512)) << 10));
        float* dst = &Bs[buf][krow * 64 + ((n0 + brot) & 63)];
#pragma unroll
        for (int j2 = 0; j2 < 4; ++j2) {
            int e0 = p0 + n0 + 2 * j2;
            int ba = e0 + off;
            int c = min(max(ba, 0), 1022);
            float2 v = *(const float2*)(plane + c);
            int y0 = e0 >> 5, xg0 = e0 & 31;
            int y1 = (e0 + 1) >> 5, xg1 = (e0 + 1) & 31;
            bool v0 = ((unsigned)(y0 + dy) < 32u) && ((unsigned)(xg0 + dx) < 32u);
            bool v1 = ((unsigned)(y1 + dy) < 32u) && ((unsigned)(xg1 + dx) < 32u);
            float2 o;
            o.x = v0 ? v.x : 0.f;
            o.y = v1 ? v.y : 0.f;
            *(float2*)(dst + 2 * j2) = o;
        }
    };

    stageA(0, 0);
    stageB(0, 0);

    for (int f = 0; f < 96; ++f) {
        const int buf = f & 1;
        __syncthreads();
        if (f < 95) {
            stageA(f + 1, buf ^ 1);
            stageB(f + 1, buf ^ 1);
        }
        bf16x8_t af[4], bfr[4];
#pragma unroll
        for (int i = 0; i < 4; ++i) {
            const char* ap = &As[buf][0] + (size_t)(w * 64 + i * 16 + m16) * 72 + quad * 16;
            union { unsigned long long d[2]; bf16x8_t v; } u;
            u.d[0] = *(const unsigned long long*)ap;
            u.d[1] = *(const unsigned long long*)(ap + 8);
            af[i] = u.v;
        }
#pragma unroll
        for (int i = 0; i < 4; ++i) {
            const float* p = &Bs[buf][0] + quad * 512 + (((i * 16 + m16) + quad * 8) & 63);
            float fv[8];
#pragma unroll
            for (int j = 0; j < 8; ++j) fv[j] = p[j * 64];
            union { unsigned u[4]; bf16x8_t v; } r;
#pragma unroll
            for (int j = 0; j < 4; ++j) {
                __hip_bfloat162 h = __float22bfloat162_rn(make_float2(fv[2 * j], fv[2 * j + 1]));
                unsigned uu;
                __builtin_memcpy(&uu, &h, 4);
                r.u[j] = uu;
            }
            bfr[i] = r.v;
        }
#pragma unroll
        for (int mi = 0; mi < 4; ++mi)
#pragma unroll
            for (int ni = 0; ni < 4; ++ni)
                acc[mi][ni] = __builtin_amdgcn_mfma_f32_16x16x32_bf16(
                    af[mi], bfr[ni], acc[mi][ni], 0, 0, 0);
    }

    float* Pb = P + (((size_t)(khg * 4 + b)) << 18) + p0;
#pragma unroll
    for (int mi = 0; mi < 4; ++mi)
#pragma unroll
        for (int e = 0; e < 4; ++e) {
            int oc = w * 64 + mi * 16 + quad * 4 + e;
            float* row = Pb + (size_t)oc * 1024 + m16;
#pragma unroll
            for (int ni = 0; ni < 4; ++ni)
                row[ni * 16] = acc[mi][ni][e];
        }
}

// ---------------------------------------------------------------------------
// Kernel 6c: x1 = relu(P0+P1+P2 + b1)
// ---------------------------------------------------------------------------
__global__ __launch_bounds__(256) void k_c1comb(const float* __restrict__ P,
                                                const float* __restrict__ b1,
                                                float* __restrict__ x1) {
    int id = blockIdx.x * 256 + threadIdx.x;  // float4 index, 0..262143
    int oc = (id >> 8) & 255;
    const float4* P4 = (const float4*)P;
    float4 a = P4[id];
    float4 bv = P4[id + 262144];
    float4 c = P4[id + 524288];
    float bb = b1[oc];
    float4 o;
    o.x = fmaxf(a.x + bv.x + c.x + bb, 0.f);
    o.y = fmaxf(a.y + bv.y + c.y + bb, 0.f);
    o.z = fmaxf(a.z + bv.z + c.z + bb, 0.f);
    o.w = fmaxf(a.w + bv.w + c.w + bb, 0.f);
    ((float4*)x1)[id] = o;
}

// ---------------------------------------------------------------------------
// Kernel 7a: pack w2 fp32 [256 oc][256 ic][9 tap] -> bf16 [tap][s(8)][oc][36]
// ---------------------------------------------------------------------------
__global__ __launch_bounds__(256) void k_w2pack(const float* __restrict__ w2,
                                                unsigned short* __restrict__ w2p) {
    int pid = blockIdx.x * 256 + threadIdx.x;  // 0..65535 = (oc,ic)
    int oc = pid >> 8, ic = pid & 255;
    const float* src = w2 + (size_t)pid * 9;
    float f[9];
#pragma unroll
    for (int tp = 0; tp < 9; ++tp) f[tp] = src[tp];
    int s = ic >> 5, j = ic & 31;
#pragma unroll
    for (int tp = 0; tp < 9; ++tp) {
        size_t row = ((size_t)(tp * 8 + s) * 256 + oc) * 36;
        w2p[row + j] = f2bf(f[tp]);
        if (j < 4) w2p[row + 32 + j] = 0;
    }
}

// ---------------------------------------------------------------------------
// Kernel 7b (MFMA): conv2 partials per kh.
// P2[kh][b][oc 256][pos 1024(32-grid)] = sum_{kw,ic} w2[oc][ic][kh][kw]*x1[ic][p+kh*32+kw]
// Valid-conv flat shift: no value masking needed (garbage columns never stored);
// only clamp addresses. Grid (16 pos, 4 b, 3 kh); K = 3 kw x 8 ic-steps.
// ---------------------------------------------------------------------------
__global__ __launch_bounds__(256) void k_conv2m(const float* __restrict__ x1,
                                                const unsigned short* __restrict__ w2p,
                                                float* __restrict__ P2) {
    __shared__ __align__(16) char As[2][18432];   // [buf][256 oc][36 bf16]
    __shared__ float Bs[2][2048];                 // [buf][32 k][64 n] rotated
    const int p0 = blockIdx.x * 64;
    const int b = blockIdx.y;
    const int kh = blockIdx.z;
    const int t = threadIdx.x;
    const int w = t >> 6, lane = t & 63;
    const int quad = lane >> 4, m16 = lane & 15;
    const int krow = t >> 3, n0 = (t & 7) * 8;
    const int brot = (krow >> 3) * 8;

    f32x4_t acc[4][4];
#pragma unroll
    for (int i = 0; i < 4; ++i)
#pragma unroll
        for (int j = 0; j < 4; ++j) acc[i][j] = (f32x4_t){0.f, 0.f, 0.f, 0.f};

    auto stageA = [&](int f, int buf) {
        int kw = f >> 3, s = f & 7;
        const char* src = (const char*)(w2p + (size_t)((kh * 3 + kw) * 8 + s) * 9216);
#pragma unroll
        for (int i = 0; i < 5; ++i) {
            int idx = i * 4 + w;
            if (idx < 18)
                __builtin_amdgcn_global_load_lds(
                    (const __attribute__((address_space(1))) void*)(src + idx * 1024 + lane * 16),
                    (__attribute__((address_space(3))) void*)(&As[buf][0] + idx * 1024),
                    16, 0, 0);
        }
    };
    auto stageB = [&](int f, int buf) {
        int kw = f >> 3, s = f & 7;
        int off = kh * 32 + kw;
        int ch = s * 32 + krow;
        const float* plane = x1 + (((size_t)(b * 256 + ch)) << 10);
        float* dst = &Bs[buf][krow * 64 + ((n0 + brot) & 63)];
#pragma unroll
        for (int j2 = 0; j2 < 4; ++j2) {
            int ba = p0 + n0 + 2 * j2 + off;
            int c = min(ba, 1022);
            *(float2*)(dst + 2 * j2) = *(const float2*)(plane + c);
        }
    };

    stageA(0, 0);
    stageB(0, 0);

    for (int f = 0; f < 24; ++f) {
        const int buf = f & 1;
        __syncthreads();
        if (f < 23) {
            stageA(f + 1, buf ^ 1);
            stageB(f + 1, buf ^ 1);
        }
        bf16x8_t af[4], bfr[4];
#pragma unroll
        for (int i = 0; i < 4; ++i) {
            const char* ap = &As[buf][0] + (size_t)(w * 64 + i * 16 + m16) * 72 + quad * 16;
            union { unsigned long long d[2]; bf16x8_t v; } u;
            u.d[0] = *(const unsigned long long*)ap;
            u.d[1] = *(const unsigned long long*)(ap + 8);
            af[i] = u.v;
        }
#pragma unroll
        for (int i = 0; i < 4; ++i) {
            const float* p = &Bs[buf][0] + quad * 512 + (((i * 16 + m16) + quad * 8) & 63);
            float fv[8];
#pragma unroll
            for (int j = 0; j < 8; ++j) fv[j] = p[j * 64];
            union { unsigned u[4]; bf16x8_t v; } r;
#pragma unroll
            for (int j = 0; j < 4; ++j) {
                __hip_bfloat162 h = __float22bfloat162_rn(make_float2(fv[2 * j], fv[2 * j + 1]));
                unsigned uu;
                __builtin_memcpy(&uu, &h, 4);
                r.u[j] = uu;
            }
            bfr[i] = r.v;
        }
#pragma unroll
        for (int mi = 0; mi < 4; ++mi)
#pragma unroll
            for (int ni = 0; ni < 4; ++ni)
                acc[mi][ni] = __builtin_amdgcn_mfma_f32_16x16x32_bf16(
                    af[mi], bfr[ni], acc[mi][ni], 0, 0, 0);
    }

    float* Pb = P2 + (((size_t)(kh * 4 + b)) << 18) + p0;
#pragma unroll
    for (int mi = 0; mi < 4; ++mi)
#pragma unroll
        for (int e = 0; e < 4; ++e) {
            int oc = w * 64 + mi * 16 + quad * 4 + e;
            float* row = Pb + (size_t)oc * 1024 + m16;
#pragma unroll
            for (int ni = 0; ni < 4; ++ni)
                row[ni * 16] = acc[mi][ni][e];
        }
}

// ---------------------------------------------------------------------------
// Kernel 7c: combine conv2 partials + bias, then 3x3/3 maxpool -> xp[4][256][100]
// ---------------------------------------------------------------------------
__global__ __launch_bounds__(256) void k_c2pool(const float* __restrict__ P2,
                                                const float* __restrict__ b2,
                                                float* __restrict__ xp) {
    int id = blockIdx.x * 256 + threadIdx.x;  // 0..102399
    int px = id % 10;
    int tmp = id / 10;
    int py = tmp % 10;
    int ch = tmp / 10;          // b*256 + oc
    int b = ch >> 8, oc = ch & 255;
    float bb = b2[oc];
    const float* base0 = P2 + (((size_t)(0 * 4 + b)) << 18) + (size_t)oc * 1024;
    const float* base1 = P2 + (((size_t)(1 * 4 + b)) << 18) + (size_t)oc * 1024;
    const float* base2 = P2 + (((size_t)(2 * 4 + b)) << 18) + (size_t)oc * 1024;
    float m = -3.4e38f;
#pragma unroll
    for (int dy = 0; dy < 3; ++dy)
#pragma unroll
        for (int dx = 0; dx < 3; ++dx) {
            int pos = (3 * py + dy) * 32 + 3 * px + dx;
            float v = base0[pos] + base1[pos] + base2[pos] + bb;
            m = fmaxf(m, v);
        }
    xp[id] = m;
}

// ---------------------------------------------------------------------------
// Kernel 9: conv3 (256ch, 10x10 -> 8x8) + spatial mean + b3 -> weight[1,B]
// ---------------------------------------------------------------------------
__global__ __launch_bounds__(256) void k_conv3(const float* __restrict__ xp,
                                               const float* __restrict__ w3,
                                               const float* __restrict__ b3,
                                               float* __restrict__ out) {
    __shared__ float s[256];
    int b = blockIdx.x, t = threadIdx.x;
    int pos = t & 63, qi = t >> 6;
    int y = pos >> 3, x = pos & 7;
    float acc = 0.f;
    for (int ic = qi * 64; ic < qi * 64 + 64; ++ic) {
        const float* ip = xp + ((size_t)(b * 256 + ic)) * 100 + y * 10 + x;
#pragma unroll
        for (int kh = 0; kh < 3; ++kh)
#pragma unroll
            for (int kw = 0; kw < 3; ++kw)
                acc = fmaf(w3[ic * 9 + kh * 3 + kw], ip[kh * 10 + kw], acc);
    }
    s[t] = acc;
    __syncthreads();
    if (t < 64) {
        float v = s[t] + s[t + 64] + s[t + 128] + s[t + 192];
#pragma unroll
        for (int off = 32; off >= 1; off >>= 1) v += __shfl_down(v, off);
        if (t == 0) out[4194304 + b] = v * (1.f / 64.f) + b3[0];
    }
}

// ---------------------------------------------------------------------------
extern "C" void kernel_launch(void* const* d_in, const int* in_sizes, int n_in,
                              void* d_out, int out_size, void* d_ws, size_t ws_size,
                              hipStream_t stream) {
    (void)in_sizes; (void)n_in; (void)out_size; (void)ws_size;
    const float* fqf = (const float*)d_in[0];  // fq_feats [9,4,512,32,32]
    const float* fsf = (const float*)d_in[1];  // fs_feats
    const float* fqi = (const float*)d_in[2];  // f_q [4,512,32,32]
    const float* fsi = (const float*)d_in[3];  // f_s
    const float* w1  = (const float*)d_in[4];
    const float* b1  = (const float*)d_in[5];
    const float* w2  = (const float*)d_in[6];
    const float* b2  = (const float*)d_in[7];
    const float* w3  = (const float*)d_in[8];
    const float* b3  = (const float*)d_in[9];
    float* out = (float*)d_out;

    float* W = (float*)d_ws;
    // Phase 1 (conv1): P [0 .. 3,145,728), w1p bf16 at W+3145728 (663,552 f32)
    float* P = W;
    unsigned short* w1p = (unsigned short*)(W + 3145728);
    // Phase 2 (attention): aliases phase-1 region (lifetimes disjoint)
    float* corr  = W;              // 4,194,304 f32, reused as attn
    float* rq    = W + 4194304;    //    36,864
    float* rs    = W + 4231168;    //    36,864
    float* attfq = W + 4268032;    // 2,097,152 (ends 6,365,184)
    // Phase 3 (conv2): aliases corr region (dead after k_attfq)
    float* P2 = W;                                   // 3,145,728 f32
    unsigned short* w2p = (unsigned short*)(W + 3145728);  // 331,776 f32 equiv
    // Persistent conv outputs
    float* x1    = W + 6365184;    // 1,048,576
    float* xp    = W + 7413760;    //   102,400  (end 7,516,160 f32 = 30 MB)

    // conv1 (scratch dies before corr is written)
    hipLaunchKernelGGL(k_w1pack,  dim3(1024),      dim3(256), 0, stream, w1, w1p);
    hipLaunchKernelGGL(k_conv1m,  dim3(16, 4, 3),  dim3(256), 0, stream, fqi, fsi, w1p, P);
    hipLaunchKernelGGL(k_c1comb,  dim3(1024),      dim3(256), 0, stream, P, b1, x1);
    // attention path
    hipLaunchKernelGGL(k_norms,   dim3(144),       dim3(256), 0, stream, fqf, fsf, rq, rs);
    hipLaunchKernelGGL(k_corr,    dim3(8, 8, 4),   dim3(256), 0, stream, fqf, fsf, rq, rs, corr);
    hipLaunchKernelGGL(k_softmax, dim3(4096),      dim3(256), 0, stream, corr);
    hipLaunchKernelGGL(k_attfq,   dim3(16, 8, 4),  dim3(256), 0, stream, fsi, corr, attfq);
    hipLaunchKernelGGL(k_out,     dim3(16, 4),     dim3(256), 0, stream, fqi, attfq, out);
    // conv tail (scratch reuses attention region, dead after k_attfq)
    hipLaunchKernelGGL(k_w2pack,  dim3(256),       dim3(256), 0, stream, w2, w2p);
    hipLaunchKernelGGL(k_conv2m,  dim3(16, 4, 3),  dim3(256), 0, stream, x1, w2p, P2);
    hipLaunchKernelGGL(k_c2pool,  dim3(400),       dim3(256), 0, stream, P2, b2, xp);
    hipLaunchKernelGGL(k_conv3,   dim3(4),         dim3(256), 0, stream, xp, w3, b3, out);
}

// Round 6
// 585.164 us; speedup vs baseline: 3.4946x; 1.2274x over previous
//
#include <hip/hip_runtime.h>
#include <hip/hip_bf16.h>

#define DI __device__ __forceinline__

typedef short bf16x8_t __attribute__((ext_vector_type(8)));
typedef _Float16 f16x8_t __attribute__((ext_vector_type(8)));
typedef float f32x4_t __attribute__((ext_vector_type(4)));

DI unsigned short f2bf(float f) {
    unsigned u = __float_as_uint(f);
    u += 0x7fffu + ((u >> 16) & 1u);
    return (unsigned short)(u >> 16);
}
DI float bfu2f(unsigned short u) { return __uint_as_float(((unsigned)u) << 16); }
DI unsigned short f2h(float f) {
    _Float16 h = (_Float16)f;
    unsigned short u;
    __builtin_memcpy(&u, &h, 2);
    return u;
}
DI float h2f(unsigned short u) {
    _Float16 h;
    __builtin_memcpy(&h, &u, 2);
    return (float)h;
}

// ---------------------------------------------------------------------------
// Kernel 1: inverse channel norms for fq_feats / fs_feats (fp32).
// ---------------------------------------------------------------------------
__global__ __launch_bounds__(256) void k_norms(const float* __restrict__ fqf,
                                               const float* __restrict__ fsf,
                                               float* __restrict__ rq,
                                               float* __restrict__ rs) {
    int id = blockIdx.x * 256 + threadIdx.x;  // 0..36863
    int tensor = id / 18432;                  // block-uniform
    int r = id % 18432;
    int lb = r >> 9;
    int pp = (r & 511) * 2;
    const float* src = tensor ? fsf : fqf;
    float* dst = tensor ? rs : rq;
    const float* p = src + (size_t)lb * 524288 + pp;
    float s0 = 0.f, s1 = 0.f;
    for (int c = 0; c < 512; ++c) {
        float2 v = *(const float2*)(p + (size_t)c * 1024);
        s0 += v.x * v.x;
        s1 += v.y * v.y;
    }
    float* d = dst + lb * 1024 + pp;
    d[0] = 1.f / fmaxf(sqrtf(s0), 1e-12f);
    d[1] = 1.f / fmaxf(sqrtf(s1), 1e-12f);
}

// ---------------------------------------------------------------------------
// Kernel 2 (MFMA): corr partials, 2-way level split (lg0: l=0,2,4,6,8; lg1:
// l=1,3,5,7). P01[lg][b][q][s] fp16. Grid (8,8,8)=512 blocks -> 2 blocks/CU.
// ---------------------------------------------------------------------------
DI void stage_tile(const float* gbase, float* lbase, int w, int lane) {
#pragma unroll
    for (int i = 0; i < 4; ++i) {
        int slot = i * 256 + w * 64 + lane;     // 16B slots 0..1023
        int r = slot >> 5;                      // row (k) 0..31
        int chp = slot & 31;                    // physical 16B chunk in row
        int msrc = ((chp * 4) - ((r >> 3) << 3)) & 127;  // un-rotated col
        __builtin_amdgcn_global_load_lds(
            (const __attribute__((address_space(1))) void*)(gbase + (size_t)r * 1024 + msrc),
            (__attribute__((address_space(3))) void*)(lbase + i * 1024 + w * 256),
            16, 0, 0);
    }
}

DI bf16x8_t build_frag(const float* base, int col, int quad) {
    const float* p = base + quad * 1024 + col;  // row quad*8, rotated col
    float f[8];
#pragma unroll
    for (int j = 0; j < 8; ++j) f[j] = p[j * 128];
    union { unsigned u[4]; bf16x8_t v; } r;
#pragma unroll
    for (int j = 0; j < 4; ++j) {
        __hip_bfloat162 h = __float22bfloat162_rn(make_float2(f[2 * j], f[2 * j + 1]));
        unsigned uu;
        __builtin_memcpy(&uu, &h, 4);
        r.u[j] = uu;
    }
    return r.v;
}

__global__ __launch_bounds__(256) void k_corr(const float* __restrict__ fqf,
                                              const float* __restrict__ fsf,
                                              const float* __restrict__ rq,
                                              const float* __restrict__ rs,
                                              unsigned short* __restrict__ P01) {
    __shared__ float As[2][4096];  // [buf][32 k x 128 m] fp32, row-rotated
    __shared__ float Bs[2][4096];
    const int b = blockIdx.z >> 1;
    const int lg = blockIdx.z & 1;
    const int q0 = blockIdx.y * 128;
    const int s0 = blockIdx.x * 128;
    const int t = threadIdx.x;
    const int w = t >> 6, lane = t & 63;
    const int wrow = w >> 1, wcol = w & 1;   // 2x2 waves of 64x64
    const int quad = lane >> 4, m16 = lane & 15;
    const int nsteps = (5 - lg) << 4;        // lg0: 80, lg1: 64

    f32x4_t zero4 = {0.f, 0.f, 0.f, 0.f};
    f32x4_t master[4][4], lvl[4][4];
#pragma unroll
    for (int i = 0; i < 4; ++i)
#pragma unroll
        for (int j = 0; j < 4; ++j) { master[i][j] = zero4; lvl[i][j] = zero4; }

    {
        const float* Ab = fqf + (size_t)(lg * 4 + b) * 524288 + q0;
        const float* Bb = fsf + (size_t)(lg * 4 + b) * 524288 + s0;
        stage_tile(Ab, &As[0][0], w, lane);
        stage_tile(Bb, &Bs[0][0], w, lane);
    }

    for (int step = 0; step < nsteps; ++step) {
        const int buf = step & 1;
        __syncthreads();
        if (step < nsteps - 1) {
            int ns = step + 1;
            int lb = (lg + 2 * (ns >> 4)) * 4 + b;
            int kk0 = (ns & 15) << 5;
            const float* Ab = fqf + (size_t)lb * 524288 + (size_t)kk0 * 1024 + q0;
            const float* Bb = fsf + (size_t)lb * 524288 + (size_t)kk0 * 1024 + s0;
            stage_tile(Ab, &As[buf ^ 1][0], w, lane);
            stage_tile(Bb, &Bs[buf ^ 1][0], w, lane);
        }
        const float* Ab = &As[buf][0];
        const float* Bb = &Bs[buf][0];
        bf16x8_t af[4], bfr[4];
#pragma unroll
        for (int i = 0; i < 4; ++i) {
            af[i]  = build_frag(Ab, ((wrow * 64 + i * 16 + m16) + quad * 8) & 127, quad);
            bfr[i] = build_frag(Bb, ((wcol * 64 + i * 16 + m16) + quad * 8) & 127, quad);
        }
#pragma unroll
        for (int mi = 0; mi < 4; ++mi)
#pragma unroll
            for (int ni = 0; ni < 4; ++ni)
                lvl[mi][ni] = __builtin_amdgcn_mfma_f32_16x16x32_bf16(
                    af[mi], bfr[ni], lvl[mi][ni], 0, 0, 0);

        if ((step & 15) == 15) {
            int lb = (lg + 2 * (step >> 4)) * 4 + b;
            const float* rqb = rq + lb * 1024 + q0 + wrow * 64;
            const float* rsb = rs + lb * 1024 + s0 + wcol * 64;
            float rq4[4][4], rsv[4];
#pragma unroll
            for (int mi = 0; mi < 4; ++mi) {
                float4 v = *(const float4*)(rqb + mi * 16 + quad * 4);
                rq4[mi][0] = v.x; rq4[mi][1] = v.y; rq4[mi][2] = v.z; rq4[mi][3] = v.w;
            }
#pragma unroll
            for (int ni = 0; ni < 4; ++ni) rsv[ni] = rsb[ni * 16 + m16];
#pragma unroll
            for (int mi = 0; mi < 4; ++mi)
#pragma unroll
                for (int ni = 0; ni < 4; ++ni) {
#pragma unroll
                    for (int e = 0; e < 4; ++e)
                        master[mi][ni][e] += fmaxf(lvl[mi][ni][e] * rq4[mi][e] * rsv[ni], 0.f);
                    lvl[mi][ni] = zero4;
                }
        }
    }

#pragma unroll
    for (int mi = 0; mi < 4; ++mi)
#pragma unroll
        for (int e = 0; e < 4; ++e) {
            int q = q0 + wrow * 64 + mi * 16 + quad * 4 + e;
            unsigned short* cp = P01 + ((((size_t)(lg * 4 + b)) * 1024 + q) << 10)
                                 + s0 + wcol * 64 + m16;
#pragma unroll
            for (int ni = 0; ni < 4; ++ni)
                cp[ni * 16] = f2h(master[mi][ni][e]);
        }
}

// ---------------------------------------------------------------------------
// Kernel 3: softmax over s. Reads 2 fp16 partials, scale 20/9, writes attn as
// padded fp16 [b][sb(32)][q][36] for MFMA staging.
// ---------------------------------------------------------------------------
__global__ __launch_bounds__(256) void k_softmax(const unsigned short* __restrict__ P01,
                                                 unsigned short* __restrict__ attn) {
    __shared__ float red[8];
    const int row = blockIdx.x;  // 0..4095
    const int b = row >> 10, q = row & 1023;
    const int t = threadIdx.x;
    const unsigned short* p0 = P01 + (((size_t)b << 20) + ((size_t)q << 10)) + t * 4;
    const unsigned short* p1 = p0 + ((size_t)4 << 20);
    uint2 a0 = *(const uint2*)p0;
    uint2 a1 = *(const uint2*)p1;
    const float SC = 20.f / 9.f;
    float v0 = (h2f(a0.x & 0xffff) + h2f(a1.x & 0xffff)) * SC;
    float v1 = (h2f(a0.x >> 16)    + h2f(a1.x >> 16)) * SC;
    float v2 = (h2f(a0.y & 0xffff) + h2f(a1.y & 0xffff)) * SC;
    float v3 = (h2f(a0.y >> 16)    + h2f(a1.y >> 16)) * SC;
    float m = fmaxf(fmaxf(v0, v1), fmaxf(v2, v3));
#pragma unroll
    for (int off = 32; off >= 1; off >>= 1) m = fmaxf(m, __shfl_down(m, off));
    const int wid = t >> 6, lane = t & 63;
    if (lane == 0) red[wid] = m;
    __syncthreads();
    m = fmaxf(fmaxf(red[0], red[1]), fmaxf(red[2], red[3]));
    float e0 = __expf(v0 - m), e1 = __expf(v1 - m);
    float e2 = __expf(v2 - m), e3 = __expf(v3 - m);
    float s = e0 + e1 + e2 + e3;
#pragma unroll
    for (int off = 32; off >= 1; off >>= 1) s += __shfl_down(s, off);
    if (lane == 0) red[4 + wid] = s;
    __syncthreads();
    s = red[4] + red[5] + red[6] + red[7];
    float inv = 1.f / s;
    unsigned short* o = attn + (size_t)((b * 32 + (t >> 3)) * 1024 + q) * 36 + (t & 7) * 4;
    uint2 r;
    r.x = (unsigned)f2h(e0 * inv) | ((unsigned)f2h(e1 * inv) << 16);
    r.y = (unsigned)f2h(e2 * inv) | ((unsigned)f2h(e3 * inv) << 16);
    *(uint2*)o = r;
}

// ---------------------------------------------------------------------------
// Kernel 4a: pack f_s fp32 [b][c][s] -> fp16 [b][sb(32)][c][36]
// ---------------------------------------------------------------------------
__global__ __launch_bounds__(256) void k_fspack(const float* __restrict__ fsi,
                                                unsigned short* __restrict__ fsp) {
    int id = blockIdx.x * 256 + threadIdx.x;  // 0..65535
    int c = id & 511, sb = (id >> 9) & 31, b = id >> 14;
    const float4* src = (const float4*)(fsi + (((size_t)(b * 512 + c)) << 10) + sb * 32);
    unsigned short* dst = fsp + (size_t)((b * 32 + sb) * 512 + c) * 36;
#pragma unroll
    for (int j = 0; j < 8; ++j) {
        float4 v = src[j];
        uint2 r;
        r.x = (unsigned)f2h(v.x) | ((unsigned)f2h(v.y) << 16);
        r.y = (unsigned)f2h(v.z) | ((unsigned)f2h(v.w) << 16);
        *(uint2*)(dst + j * 4) = r;
    }
}

// ---------------------------------------------------------------------------
// Kernel 4b (MFMA f16): att_fq[b,c,q] = sum_s attn[q,s] * f_s[c,s]
// Tile 64c x 128q, K=1024 (32 steps of BK=32). A/B rows padded to 36 halves;
// flat-memcpy global_load_lds staging; frags = single ds_read_b128.
// ---------------------------------------------------------------------------
__global__ __launch_bounds__(256) void k_attfqm(const unsigned short* __restrict__ fsp,
                                                const unsigned short* __restrict__ attn,
                                                float* __restrict__ attfq) {
    __shared__ __align__(16) char L[2][14336];  // A 4608 B | B 9216 B | pad 512
    const int q0 = blockIdx.x * 128;
    const int c0 = blockIdx.y * 64;
    const int b  = blockIdx.z;
    const int t = threadIdx.x;
    const int w = t >> 6, lane = t & 63;
    const int quad = lane >> 4, m16 = lane & 15;

    f32x4_t acc[4][2];
#pragma unroll
    for (int i = 0; i < 4; ++i)
#pragma unroll
        for (int j = 0; j < 2; ++j) acc[i][j] = (f32x4_t){0.f, 0.f, 0.f, 0.f};

    auto stage = [&](int sb, int buf) {
        const char* sa = (const char*)(fsp + (size_t)((b * 32 + sb) * 512 + c0) * 36);
        const char* sbp = (const char*)(attn + (size_t)((b * 32 + sb) * 1024 + q0) * 36);
#pragma unroll
        for (int i = 0; i < 4; ++i) {
            int idx0 = i * 256 + w * 64;          // wave-uniform chunk base
            if (idx0 < 896) {                      // uniform predicate (pad reads ok)
                int idx = idx0 + lane;
                const char* src = (idx < 288) ? (sa + idx * 16) : (sbp + (idx - 288) * 16);
                __builtin_amdgcn_global_load_lds(
                    (const __attribute__((address_space(1))) void*)src,
                    (__attribute__((address_space(3))) void*)(&L[buf][0] + idx0 * 16),
                    16, 0, 0);
            }
        }
    };

    stage(0, 0);
    for (int sb = 0; sb < 32; ++sb) {
        const int buf = sb & 1;
        __syncthreads();
        if (sb < 31) stage(sb + 1, buf ^ 1);
        const char* base = &L[buf][0];
        f16x8_t af[4], bfr[2];
#pragma unroll
        for (int i = 0; i < 4; ++i) {
            const char* ap = base + (size_t)(i * 16 + m16) * 72 + quad * 16;
            union { unsigned long long d[2]; f16x8_t v; } u;
            u.d[0] = *(const unsigned long long*)ap;
            u.d[1] = *(const unsigned long long*)(ap + 8);
            af[i] = u.v;
        }
#pragma unroll
        for (int ni = 0; ni < 2; ++ni) {
            const char* bp = base + 4608 + (size_t)(w * 32 + ni * 16 + m16) * 72 + quad * 16;
            union { unsigned long long d[2]; f16x8_t v; } u;
            u.d[0] = *(const unsigned long long*)bp;
            u.d[1] = *(const unsigned long long*)(bp + 8);
            bfr[ni] = u.v;
        }
#pragma unroll
        for (int mi = 0; mi < 4; ++mi)
#pragma unroll
            for (int ni = 0; ni < 2; ++ni)
                acc[mi][ni] = __builtin_amdgcn_mfma_f32_16x16x32_f16(
                    af[mi], bfr[ni], acc[mi][ni], 0, 0, 0);
    }

#pragma unroll
    for (int mi = 0; mi < 4; ++mi)
#pragma unroll
        for (int e = 0; e < 4; ++e) {
            int c = c0 + mi * 16 + quad * 4 + e;
            float* rowp = attfq + (((size_t)(b * 512 + c)) << 10) + q0 + w * 32 + m16;
#pragma unroll
            for (int ni = 0; ni < 2; ++ni)
                rowp[ni * 16] = acc[mi][ni][e];
        }
}

// ---------------------------------------------------------------------------
// Kernel 5: fq = l2n(f_q,C) + 0.5*l2n(att_fq,C); write fq & att_fq (fp32).
// ---------------------------------------------------------------------------
__global__ __launch_bounds__(256) void k_out(const float* __restrict__ fqi,
                                             const float* __restrict__ attfq,
                                             float* __restrict__ out) {
    __shared__ float redq[256], reda[256];
    __shared__ float rnq[64], rna[64];
    const int b = blockIdx.y;
    const int p0 = blockIdx.x * 64;
    const int t = threadIdx.x;
    const int pl = t & 63, cg = t >> 6;
    const int pos = p0 + pl;
    const float* qp = fqi + (((size_t)b) << 19) + pos;
    const float* ap = attfq + (((size_t)b) << 19) + pos;
    float sq = 0.f, sa = 0.f;
    for (int c = cg * 128; c < cg * 128 + 128; ++c) {
        float q = qp[(size_t)c << 10];
        float a = ap[(size_t)c << 10];
        sq += q * q;
        sa += a * a;
    }
    redq[t] = sq; reda[t] = sa;
    __syncthreads();
    if (t < 64) {
        float q = redq[t] + redq[t + 64] + redq[t + 128] + redq[t + 192];
        float a = reda[t] + reda[t + 64] + reda[t + 128] + reda[t + 192];
        rnq[t] = 1.f / fmaxf(sqrtf(q), 1e-12f);
        rna[t] = 1.f / fmaxf(sqrtf(a), 1e-12f);
    }
    __syncthreads();
    const float RQ = rnq[pl], RA = 0.5f * rna[pl];
    float* o1 = out + (((size_t)b) << 19) + pos;
    float* o2 = o1 + 2097152;
    for (int c = cg * 128; c < cg * 128 + 128; ++c) {
        float q = qp[(size_t)c << 10];
        float a = ap[(size_t)c << 10];
        o1[(size_t)c << 10] = q * RQ + a * RA;
        o2[(size_t)c << 10] = a;
    }
}

// ---------------------------------------------------------------------------
// Kernel 6a: pack w1 fp32 [256 oc][1024 ic][9 tap] -> bf16 [tap][s][oc][36]
// ---------------------------------------------------------------------------
__global__ __launch_bounds__(256) void k_w1pack(const float* __restrict__ w1,
                                                unsigned short* __restrict__ w1p) {
    int pid = blockIdx.x * 256 + threadIdx.x;  // 0..262143 = (oc,ic)
    int oc = pid >> 10, ic = pid & 1023;
    const float* src = w1 + (size_t)pid * 9;
    float f[9];
#pragma unroll
    for (int tp = 0; tp < 9; ++tp) f[tp] = src[tp];
    int s = ic >> 5, j = ic & 31;
#pragma unroll
    for (int tp = 0; tp < 9; ++tp) {
        size_t row = ((size_t)(tp * 32 + s) * 256 + oc) * 36;
        w1p[row + j] = f2bf(f[tp]);
        if (j < 4) w1p[row + 32 + j] = 0;
    }
}

// ---------------------------------------------------------------------------
// Kernel 6b (MFMA): conv1 partials per kh-group. (verified)
// ---------------------------------------------------------------------------
__global__ __launch_bounds__(256) void k_conv1m(const float* __restrict__ fqi,
                                                const float* __restrict__ fsi,
                                                const unsigned short* __restrict__ w1p,
                                                float* __restrict__ P) {
    __shared__ __align__(16) char As[2][18432];   // [buf][256 oc][36 bf16]
    __shared__ float Bs[2][2048];                 // [buf][32 k][64 n] rotated
    const int p0 = blockIdx.x * 64;
    const int b = blockIdx.y;
    const int khg = blockIdx.z;
    const int dy = 2 * khg - 2;
    const int t = threadIdx.x;
    const int w = t >> 6, lane = t & 63;
    const int quad = lane >> 4, m16 = lane & 15;
    const int krow = t >> 3, n0 = (t & 7) * 8;   // B-staging coords
    const int brot = (krow >> 3) * 8;

    f32x4_t acc[4][4];
#pragma unroll
    for (int i = 0; i < 4; ++i)
#pragma unroll
        for (int j = 0; j < 4; ++j) acc[i][j] = (f32x4_t){0.f, 0.f, 0.f, 0.f};

    auto stageA = [&](int f, int buf) {
        int kw = f >> 5, s = f & 31;
        const char* src = (const char*)(w1p + (size_t)((khg * 3 + kw) * 32 + s) * 9216);
#pragma unroll
        for (int i = 0; i < 5; ++i) {
            int idx = i * 4 + w;
            if (idx < 18)
                __builtin_amdgcn_global_load_lds(
                    (const __attribute__((address_space(1))) void*)(src + idx * 1024 + lane * 16),
                    (__attribute__((address_space(3))) void*)(&As[buf][0] + idx * 1024),
                    16, 0, 0);
        }
    };
    auto stageB = [&](int f, int buf) {
        int kw = f >> 5, s = f & 31;
        int dx = 2 * kw - 2;
        int off = dy * 32 + dx;
        int ch = s * 32 + krow;
        const float* plane = (ch < 512)
            ? (fqi + (((size_t)(b * 512 + ch)) << 10))
            : (fsi + (((size_t)(b * 512 + ch - 512)) << 10));
        float* dst = &Bs[buf][krow * 64 + ((n0 + brot) & 63)];
#pragma unroll
        for (int j2 = 0; j2 < 4; ++j2) {
            int e0 = p0 + n0 + 2 * j2;
            int ba = e0 + off;
            int c = min(max(ba, 0), 1022);
            float2 v = *(const float2*)(plane + c);
            int y0 = e0 >> 5, xg0 = e0 & 31;
            int y1 = (e0 + 1) >> 5, xg1 = (e0 + 1) & 31;
            bool v0 = ((unsigned)(y0 + dy) < 32u) && ((unsigned)(xg0 + dx) < 32u);
            bool v1 = ((unsigned)(y1 + dy) < 32u) && ((unsigned)(xg1 + dx) < 32u);
            float2 o;
            o.x = v0 ? v.x : 0.f;
            o.y = v1 ? v.y : 0.f;
            *(float2*)(dst + 2 * j2) = o;
        }
    };

    stageA(0, 0);
    stageB(0, 0);

    for (int f = 0; f < 96; ++f) {
        const int buf = f & 1;
        __syncthreads();
        if (f < 95) {
            stageA(f + 1, buf ^ 1);
            stageB(f + 1, buf ^ 1);
        }
        bf16x8_t af[4], bfr[4];
#pragma unroll
        for (int i = 0; i < 4; ++i) {
            const char* ap = &As[buf][0] + (size_t)(w * 64 + i * 16 + m16) * 72 + quad * 16;
            union { unsigned long long d[2]; bf16x8_t v; } u;
            u.d[0] = *(const unsigned long long*)ap;
            u.d[1] = *(const unsigned long long*)(ap + 8);
            af[i] = u.v;
        }
#pragma unroll
        for (int i = 0; i < 4; ++i) {
            const float* p = &Bs[buf][0] + quad * 512 + (((i * 16 + m16) + quad * 8) & 63);
            float fv[8];
#pragma unroll
            for (int j = 0; j < 8; ++j) fv[j] = p[j * 64];
            union { unsigned u[4]; bf16x8_t v; } r;
#pragma unroll
            for (int j = 0; j < 4; ++j) {
                __hip_bfloat162 h = __float22bfloat162_rn(make_float2(fv[2 * j], fv[2 * j + 1]));
                unsigned uu;
                __builtin_memcpy(&uu, &h, 4);
                r.u[j] = uu;
            }
            bfr[i] = r.v;
        }
#pragma unroll
        for (int mi = 0; mi < 4; ++mi)
#pragma unroll
            for (int ni = 0; ni < 4; ++ni)
                acc[mi][ni] = __builtin_amdgcn_mfma_f32_16x16x32_bf16(
                    af[mi], bfr[ni], acc[mi][ni], 0, 0, 0);
    }

    float* Pb = P + (((size_t)(khg * 4 + b)) << 18) + p0;
#pragma unroll
    for (int mi = 0; mi < 4; ++mi)
#pragma unroll
        for (int e = 0; e < 4; ++e) {
            int oc = w * 64 + mi * 16 + quad * 4 + e;
            float* row = Pb + (size_t)oc * 1024 + m16;
#pragma unroll
            for (int ni = 0; ni < 4; ++ni)
                row[ni * 16] = acc[mi][ni][e];
        }
}

// ---------------------------------------------------------------------------
// Kernel 6c: x1 = relu(P0+P1+P2 + b1), stored bf16
// ---------------------------------------------------------------------------
__global__ __launch_bounds__(256) void k_c1comb(const float* __restrict__ P,
                                                const float* __restrict__ b1,
                                                unsigned short* __restrict__ x1) {
    int id = blockIdx.x * 256 + threadIdx.x;  // 4-elem index, 0..262143
    int oc = (id >> 8) & 255;
    const float4* P4 = (const float4*)P;
    float4 a = P4[id];
    float4 bv = P4[id + 262144];
    float4 c = P4[id + 524288];
    float bb = b1[oc];
    float o0 = fmaxf(a.x + bv.x + c.x + bb, 0.f);
    float o1 = fmaxf(a.y + bv.y + c.y + bb, 0.f);
    float o2 = fmaxf(a.z + bv.z + c.z + bb, 0.f);
    float o3 = fmaxf(a.w + bv.w + c.w + bb, 0.f);
    uint2 r;
    r.x = (unsigned)f2bf(o0) | ((unsigned)f2bf(o1) << 16);
    r.y = (unsigned)f2bf(o2) | ((unsigned)f2bf(o3) << 16);
    ((uint2*)x1)[id] = r;
}

// ---------------------------------------------------------------------------
// Kernel 7a: pack w2 fp32 [256 oc][256 ic][9 tap] -> bf16 [tap][s(8)][oc][36]
// ---------------------------------------------------------------------------
__global__ __launch_bounds__(256) void k_w2pack(const float* __restrict__ w2,
                                                unsigned short* __restrict__ w2p) {
    int pid = blockIdx.x * 256 + threadIdx.x;  // 0..65535 = (oc,ic)
    int oc = pid >> 8, ic = pid & 255;
    const float* src = w2 + (size_t)pid * 9;
    float f[9];
#pragma unroll
    for (int tp = 0; tp < 9; ++tp) f[tp] = src[tp];
    int s = ic >> 5, j = ic & 31;
#pragma unroll
    for (int tp = 0; tp < 9; ++tp) {
        size_t row = ((size_t)(tp * 8 + s) * 256 + oc) * 36;
        w2p[row + j] = f2bf(f[tp]);
        if (j < 4) w2p[row + 32 + j] = 0;
    }
}

// ---------------------------------------------------------------------------
// Kernel 7b (MFMA): conv2 partials per kh (x1 now bf16).
// ---------------------------------------------------------------------------
__global__ __launch_bounds__(256) void k_conv2m(const unsigned short* __restrict__ x1,
                                                const unsigned short* __restrict__ w2p,
                                                float* __restrict__ P2) {
    __shared__ __align__(16) char As[2][18432];   // [buf][256 oc][36 bf16]
    __shared__ float Bs[2][2048];                 // [buf][32 k][64 n] rotated
    const int p0 = blockIdx.x * 64;
    const int b = blockIdx.y;
    const int kh = blockIdx.z;
    const int t = threadIdx.x;
    const int w = t >> 6, lane = t & 63;
    const int quad = lane >> 4, m16 = lane & 15;
    const int krow = t >> 3, n0 = (t & 7) * 8;
    const int brot = (krow >> 3) * 8;

    f32x4_t acc[4][4];
#pragma unroll
    for (int i = 0; i < 4; ++i)
#pragma unroll
        for (int j = 0; j < 4; ++j) acc[i][j] = (f32x4_t){0.f, 0.f, 0.f, 0.f};

    auto stageA = [&](int f, int buf) {
        int kw = f >> 3, s = f & 7;
        const char* src = (const char*)(w2p + (size_t)((kh * 3 + kw) * 8 + s) * 9216);
#pragma unroll
        for (int i = 0; i < 5; ++i) {
            int idx = i * 4 + w;
            if (idx < 18)
                __builtin_amdgcn_global_load_lds(
                    (const __attribute__((address_space(1))) void*)(src + idx * 1024 + lane * 16),
                    (__attribute__((address_space(3))) void*)(&As[buf][0] + idx * 1024),
                    16, 0, 0);
        }
    };
    auto stageB = [&](int f, int buf) {
        int kw = f >> 3, s = f & 7;
        int off = kh * 32 + kw;
        int ch = s * 32 + krow;
        const unsigned short* plane = x1 + (((size_t)(b * 256 + ch)) << 10);
        float* dst = &Bs[buf][krow * 64 + ((n0 + brot) & 63)];
#pragma unroll
        for (int j2 = 0; j2 < 4; ++j2) {
            int ba = p0 + n0 + 2 * j2 + off;
            int c = min(ba, 1022);
            float2 o;
            o.x = bfu2f(plane[c]);
            o.y = bfu2f(plane[c + 1]);
            *(float2*)(dst + 2 * j2) = o;
        }
    };

    stageA(0, 0);
    stageB(0, 0);

    for (int f = 0; f < 24; ++f) {
        const int buf = f & 1;
        __syncthreads();
        if (f < 23) {
            stageA(f + 1, buf ^ 1);
            stageB(f + 1, buf ^ 1);
        }
        bf16x8_t af[4], bfr[4];
#pragma unroll
        for (int i = 0; i < 4; ++i) {
            const char* ap = &As[buf][0] + (size_t)(w * 64 + i * 16 + m16) * 72 + quad * 16;
            union { unsigned long long d[2]; bf16x8_t v; } u;
            u.d[0] = *(const unsigned long long*)ap;
            u.d[1] = *(const unsigned long long*)(ap + 8);
            af[i] = u.v;
        }
#pragma unroll
        for (int i = 0; i < 4; ++i) {
            const float* p = &Bs[buf][0] + quad * 512 + (((i * 16 + m16) + quad * 8) & 63);
            float fv[8];
#pragma unroll
            for (int j = 0; j < 8; ++j) fv[j] = p[j * 64];
            union { unsigned u[4]; bf16x8_t v; } r;
#pragma unroll
            for (int j = 0; j < 4; ++j) {
                __hip_bfloat162 h = __float22bfloat162_rn(make_float2(fv[2 * j], fv[2 * j + 1]));
                unsigned uu;
                __builtin_memcpy(&uu, &h, 4);
                r.u[j] = uu;
            }
            bfr[i] = r.v;
        }
#pragma unroll
        for (int mi = 0; mi < 4; ++mi)
#pragma unroll
            for (int ni = 0; ni < 4; ++ni)
                acc[mi][ni] = __builtin_amdgcn_mfma_f32_16x16x32_bf16(
                    af[mi], bfr[ni], acc[mi][ni], 0, 0, 0);
    }

    float* Pb = P2 + (((size_t)(kh * 4 + b)) << 18) + p0;
#pragma unroll
    for (int mi = 0; mi < 4; ++mi)
#pragma unroll
        for (int e = 0; e < 4; ++e) {
            int oc = w * 64 + mi * 16 + quad * 4 + e;
            float* row = Pb + (size_t)oc * 1024 + m16;
#pragma unroll
            for (int ni = 0; ni < 4; ++ni)
                row[ni * 16] = acc[mi][ni][e];
        }
}

// ---------------------------------------------------------------------------
// Kernel 7c: combine conv2 partials + bias, then 3x3/3 maxpool -> xp[4][256][100]
// ---------------------------------------------------------------------------
__global__ __launch_bounds__(256) void k_c2pool(const float* __restrict__ P2,
                                                const float* __restrict__ b2,
                                                float* __restrict__ xp) {
    int id = blockIdx.x * 256 + threadIdx.x;  // 0..102399
    int px = id % 10;
    int tmp = id / 10;
    int py = tmp % 10;
    int ch = tmp / 10;          // b*256 + oc
    int b = ch >> 8, oc = ch & 255;
    float bb = b2[oc];
    const float* base0 = P2 + (((size_t)(0 * 4 + b)) << 18) + (size_t)oc * 1024;
    const float* base1 = P2 + (((size_t)(1 * 4 + b)) << 18) + (size_t)oc * 1024;
    const float* base2 = P2 + (((size_t)(2 * 4 + b)) << 18) + (size_t)oc * 1024;
    float m = -3.4e38f;
#pragma unroll
    for (int dy = 0; dy < 3; ++dy)
#pragma unroll
        for (int dx = 0; dx < 3; ++dx) {
            int pos = (3 * py + dy) * 32 + 3 * px + dx;
            float v = base0[pos] + base1[pos] + base2[pos] + bb;
            m = fmaxf(m, v);
        }
    xp[id] = m;
}

// ---------------------------------------------------------------------------
// Kernel 9: conv3 (256ch, 10x10 -> 8x8) + spatial mean + b3 -> weight[1,B]
// ---------------------------------------------------------------------------
__global__ __launch_bounds__(256) void k_conv3(const float* __restrict__ xp,
                                               const float* __restrict__ w3,
                                               const float* __restrict__ b3,
                                               float* __restrict__ out) {
    __shared__ float s[256];
    int b = blockIdx.x, t = threadIdx.x;
    int pos = t & 63, qi = t >> 6;
    int y = pos >> 3, x = pos & 7;
    float acc = 0.f;
    for (int ic = qi * 64; ic < qi * 64 + 64; ++ic) {
        const float* ip = xp + ((size_t)(b * 256 + ic)) * 100 + y * 10 + x;
#pragma unroll
        for (int kh = 0; kh < 3; ++kh)
#pragma unroll
            for (int kw = 0; kw < 3; ++kw)
                acc = fmaf(w3[ic * 9 + kh * 3 + kw], ip[kh * 10 + kw], acc);
    }
    s[t] = acc;
    __syncthreads();
    if (t < 64) {
        float v = s[t] + s[t + 64] + s[t + 128] + s[t + 192];
#pragma unroll
        for (int off = 32; off >= 1; off >>= 1) v += __shfl_down(v, off);
        if (t == 0) out[4194304 + b] = v * (1.f / 64.f) + b3[0];
    }
}

// ---------------------------------------------------------------------------
extern "C" void kernel_launch(void* const* d_in, const int* in_sizes, int n_in,
                              void* d_out, int out_size, void* d_ws, size_t ws_size,
                              hipStream_t stream) {
    (void)in_sizes; (void)n_in; (void)out_size; (void)ws_size;
    const float* fqf = (const float*)d_in[0];  // fq_feats [9,4,512,32,32]
    const float* fsf = (const float*)d_in[1];  // fs_feats
    const float* fqi = (const float*)d_in[2];  // f_q [4,512,32,32]
    const float* fsi = (const float*)d_in[3];  // f_s
    const float* w1  = (const float*)d_in[4];
    const float* b1  = (const float*)d_in[5];
    const float* w2  = (const float*)d_in[6];
    const float* b2  = (const float*)d_in[7];
    const float* w3  = (const float*)d_in[8];
    const float* b3  = (const float*)d_in[9];
    float* out = (float*)d_out;

    float* W = (float*)d_ws;
    // [0 .. 4,194,304) f32:  P01 fp16 corr partials (8.4M ush); also aliased by
    //   conv1 P (3.1M f32, pre-corr), attfq fp32 (2.1M, post-softmax),
    //   conv2 P2 (3.1M f32, post-k_out)
    unsigned short* P01u = (unsigned short*)W;
    float* P     = W;
    float* attfq = W;
    float* P2    = W;
    // [4,194,304 .. 6,553,600): attn fp16 padded (4.7M ush); aliased by w1p
    //   (1.33M f32, dead after conv1m), rq/rs (dead after k_corr), w2p (post-attn)
    unsigned short* attn = (unsigned short*)(W + 4194304);
    unsigned short* w1p  = (unsigned short*)(W + 4194304);
    float* rq = W + 5521408;
    float* rs = W + 5558272;
    unsigned short* w2p  = (unsigned short*)(W + 4194304);
    // [6,553,600 .. 7,733,248): fs fp16 padded (2.36M ush)
    unsigned short* fsp = (unsigned short*)(W + 6553600);
    // [7,733,248 .. 8,257,536): x1 bf16 (1.05M ush)
    unsigned short* x1 = (unsigned short*)(W + 7733248);
    // [8,257,536 .. 8,359,936): xp fp32  (total 33.4 MB)
    float* xp = W + 8257536;

    // conv1 phase (scratch in P01/attn regions, dead before k_corr/softmax)
    hipLaunchKernelGGL(k_w1pack,  dim3(1024),      dim3(256), 0, stream, w1, w1p);
    hipLaunchKernelGGL(k_conv1m,  dim3(16, 4, 3),  dim3(256), 0, stream, fqi, fsi, w1p, P);
    hipLaunchKernelGGL(k_c1comb,  dim3(1024),      dim3(256), 0, stream, P, b1, x1);
    hipLaunchKernelGGL(k_fspack,  dim3(256),       dim3(256), 0, stream, fsi, fsp);
    // attention path
    hipLaunchKernelGGL(k_norms,   dim3(144),       dim3(256), 0, stream, fqf, fsf, rq, rs);
    hipLaunchKernelGGL(k_corr,    dim3(8, 8, 8),   dim3(256), 0, stream, fqf, fsf, rq, rs, P01u);
    hipLaunchKernelGGL(k_softmax, dim3(4096),      dim3(256), 0, stream, P01u, attn);
    hipLaunchKernelGGL(k_attfqm,  dim3(8, 8, 4),   dim3(256), 0, stream, fsp, attn, attfq);
    hipLaunchKernelGGL(k_out,     dim3(16, 4),     dim3(256), 0, stream, fqi, attfq, out);
    // conv tail (scratch reuses attention regions, dead after k_out)
    hipLaunchKernelGGL(k_w2pack,  dim3(256),       dim3(256), 0, stream, w2, w2p);
    hipLaunchKernelGGL(k_conv2m,  dim3(16, 4, 3),  dim3(256), 0, stream, x1, w2p, P2);
    hipLaunchKernelGGL(k_c2pool,  dim3(400),       dim3(256), 0, stream, P2, b2, xp);
    hipLaunchKernelGGL(k_conv3,   dim3(4),         dim3(256), 0, stream, xp, w3, b3, out);
}